// Round 3
// baseline (1153.512 us; speedup 1.0000x reference)
//
#include <hip/hip_runtime.h>
#include <hip/hip_bf16.h>

#define HH 4
#define NR 20000
#define DIN 257
#define DS 256
#define MF 64
#define KP 288   // padded K for bf16 staging (9 chunks of 32)
#define NKC 32
#define LTP 272  // lastT padded d-rows (17 strips of 16)

typedef __bf16 bf16;
typedef bf16 bf16x8 __attribute__((ext_vector_type(8)));
typedef bf16 bf16x4 __attribute__((ext_vector_type(4)));
typedef float f32x4 __attribute__((ext_vector_type(4)));

__device__ __forceinline__ void load_lds16(const void* g, void* l) {
  __builtin_amdgcn_global_load_lds((const __attribute__((address_space(1))) void*)g,
                                   (__attribute__((address_space(3))) void*)l,
                                   16, 0, 0);
}

// ---------------------------------------------------------------------------
// conversion kernels
// ---------------------------------------------------------------------------
__global__ void cvt_x_kernel(const float* __restrict__ x, bf16* __restrict__ xb) {
  const int n = blockIdx.x, k = threadIdx.x;  // 288 threads
  xb[(long)n * KP + k] = (k < DIN) ? (bf16)x[(long)n * DIN + k] : (bf16)0.f;
}

__global__ void cvt_w_kernel(const float* __restrict__ Wq, const float* __restrict__ Wk,
                             const float* __restrict__ Wv, bf16* __restrict__ WbTq,
                             bf16* __restrict__ WbTk, bf16* __restrict__ WbTv) {
  const int which = blockIdx.y;
  const int h = blockIdx.x >> 8, n = blockIdx.x & 255, k = threadIdx.x;
  const float* W = which == 0 ? Wq : (which == 1 ? Wk : Wv);
  bf16* o = which == 0 ? WbTq : (which == 1 ? WbTk : WbTv);
  o[((long)h * 256 + n) * KP + k] =
      (k < DIN) ? (bf16)W[((long)h * DIN + k) * DS + n] : (bf16)0.f;
}

__global__ void cvt_p_kernel(const float* __restrict__ proj, bf16* __restrict__ projT) {
  const int nm = blockIdx.x, k = threadIdx.x;  // 64 x 256
  projT[nm * 256 + k] = (bf16)proj[(long)k * MF + nm];
}

// ---------------------------------------------------------------------------
// MFMA projection kernel (unchanged from round 2).
// ---------------------------------------------------------------------------
template <int MODE>
__global__ __launch_bounds__(256) void proj_kernel(
    const bf16* __restrict__ xb, const bf16* __restrict__ WbT,
    const float* __restrict__ b, const bf16* __restrict__ projT,
    float* __restrict__ vout, bf16* __restrict__ fout)
{
  __shared__ __align__(16) unsigned char smem[35072];
  bf16* As = (bf16*)smem;              // [64][40]
  bf16* Bs = (bf16*)(smem + 5120);     // [4][256][8]
  bf16* Ss = (bf16*)smem;              // phase2: [64][264]
  float* rs = (float*)(smem + 33792);  // [64][4]
  float* fr = (float*)(smem + 34816);  // [64]

  const int t = threadIdx.x;
  const int h = blockIdx.y;
  const int n0 = blockIdx.x * 64;
  const int w = t >> 6, lane = t & 63;
  const int m16 = lane & 15, q = lane >> 4;

  f32x4 acc[4][4] = {};
  const bf16* wbh = WbT + (long)h * 256 * KP;

  for (int c = 0; c < 9; c++) {
    const int k0 = c * 32;
    {
      const int row = t >> 2, ko = (t & 3) * 8;
      const int rv = min(n0 + row, NR - 1);
      bf16x8 av = *(const bf16x8*)(xb + (long)rv * KP + k0 + ko);
      *(bf16x8*)(As + row * 40 + ko) = av;
    }
    {
      const bf16* gb = wbh + k0 + w * 8;
      for (int s = 0; s < 4; s++) {
        const int n = s * 64 + lane;
        load_lds16(gb + (long)n * KP, Bs + w * 2048 + s * 512);
      }
    }
    __syncthreads();
    bf16x8 af[4], bfj[4];
#pragma unroll
    for (int i = 0; i < 4; i++)
      af[i] = *(const bf16x8*)(As + (i * 16 + m16) * 40 + q * 8);
#pragma unroll
    for (int j = 0; j < 4; j++)
      bfj[j] = *(const bf16x8*)(Bs + q * 2048 + (w * 64 + j * 16 + m16) * 8);
#pragma unroll
    for (int i = 0; i < 4; i++)
#pragma unroll
      for (int j = 0; j < 4; j++)
        acc[i][j] = __builtin_amdgcn_mfma_f32_16x16x32_bf16(af[i], bfj[j], acc[i][j], 0, 0, 0);
    __syncthreads();
  }

  float bias[4];
#pragma unroll
  for (int j = 0; j < 4; j++) bias[j] = b[h * DS + w * 64 + j * 16 + m16];
#pragma unroll
  for (int i = 0; i < 4; i++)
#pragma unroll
    for (int j = 0; j < 4; j++)
#pragma unroll
      for (int r = 0; r < 4; r++) acc[i][j][r] += bias[j];

#pragma unroll
  for (int i = 0; i < 4; i++)
#pragma unroll
    for (int r = 0; r < 4; r++) {
      float s = acc[i][0][r] * acc[i][0][r] + acc[i][1][r] * acc[i][1][r] +
                acc[i][2][r] * acc[i][2][r] + acc[i][3][r] * acc[i][3][r];
      for (int off = 1; off < 16; off <<= 1) s += __shfl_xor(s, off);
      if (m16 == 0) rs[(i * 16 + q * 4 + r) * 4 + w] = s;
    }
  __syncthreads();

  if (MODE == 0) {
    if (t < 64) {
      const float ss = rs[t * 4] + rs[t * 4 + 1] + rs[t * 4 + 2] + rs[t * 4 + 3];
      if (n0 + t < NR) vout[((long)h * NR + n0 + t) * DIN] = sqrtf(1.f + ss);
    }
#pragma unroll
    for (int i = 0; i < 4; i++) {
      const int row = i * 16 + q * 4;
#pragma unroll
      for (int r = 0; r < 4; r++) {
        const int rg = n0 + row + r;
        if (rg < NR) {
          float* vo = vout + ((long)h * NR + rg) * DIN + 1 + w * 64 + m16;
          vo[0] = acc[i][0][r]; vo[16] = acc[i][1][r];
          vo[32] = acc[i][2][r]; vo[48] = acc[i][3][r];
        }
      }
    }
  } else {
    if (t < 64) {
      const float ss = rs[t * 4] + rs[t * 4 + 1] + rs[t * 4 + 2] + rs[t * 4 + 3];
      fr[t] = 0.125f * __expf(-ss) + 1e-8f;
    }
#pragma unroll
    for (int i = 0; i < 4; i++)
#pragma unroll
      for (int j = 0; j < 4; j++)
#pragma unroll
        for (int r = 0; r < 4; r++)
          Ss[(i * 16 + q * 4 + r) * 264 + w * 64 + j * 16 + m16] = (bf16)acc[i][j][r];
    __syncthreads();
    f32x4 fc[4] = {};
    const bf16* pT = projT + (w * 16 + m16) * 256 + q * 8;
#pragma unroll
    for (int s = 0; s < 8; s++) {
      bf16x8 pb = *(const bf16x8*)(pT + s * 32);
#pragma unroll
      for (int i = 0; i < 4; i++) {
        bf16x8 sa = *(const bf16x8*)(Ss + (i * 16 + m16) * 264 + s * 32 + q * 8);
        fc[i] = __builtin_amdgcn_mfma_f32_16x16x32_bf16(sa, pb, fc[i], 0, 0, 0);
      }
    }
    const float SQ2 = 1.41421356237309515f;
#pragma unroll
    for (int i = 0; i < 4; i++) {
      const int row = i * 16 + q * 4;
#pragma unroll
      for (int r = 0; r < 4; r++) {
        const int rg = n0 + row + r;
        if (rg < NR)
          fout[((long)h * NR + rg) * MF + w * 16 + m16] =
              (bf16)(__expf(SQ2 * fc[i][r]) * fr[row + r]);
      }
    }
  }
}

// ---------------------------------------------------------------------------
// lastT split-K partials (unchanged)
// ---------------------------------------------------------------------------
__global__ __launch_bounds__(256) void last_kernel(
    const float* __restrict__ v, const bf16* __restrict__ f,
    float* __restrict__ part)
{
  __shared__ __align__(16) float Al[16][68];
  __shared__ __align__(16) float Bl[16][64];
  const int t = threadIdx.x;
  const int dt = blockIdx.x, kc = blockIdx.y, h = blockIdx.z;
  const int d0 = dt * 64;
  const int nbeg = kc * 625, nend = nbeg + 625;
  const int lr = t >> 4, lc4 = (t & 15) * 4;
  const int dm = (t & 15) * 4, mm = (t >> 4) * 4;
  float acc[4][4];
#pragma unroll
  for (int i = 0; i < 4; i++)
#pragma unroll
    for (int j = 0; j < 4; j++) acc[i][j] = 0.f;

  for (int n0 = nbeg; n0 < nend; n0 += 16) {
    const int nr = min(16, nend - n0);
    float av[4] = {0.f, 0.f, 0.f, 0.f};
    float4 bf = make_float4(0.f, 0.f, 0.f, 0.f);
    if (lr < nr) {
      const float* src = v + ((long)h * NR + n0 + lr) * DIN + d0 + lc4;
#pragma unroll
      for (int j = 0; j < 4; j++) av[j] = (d0 + lc4 + j < DIN) ? src[j] : 0.f;
      bf16x4 b4 = *(const bf16x4*)(f + ((long)h * NR + n0 + lr) * MF + lc4);
      bf = make_float4((float)b4[0], (float)b4[1], (float)b4[2], (float)b4[3]);
    }
    *(float4*)&Al[lr][lc4] = make_float4(av[0], av[1], av[2], av[3]);
    *(float4*)&Bl[lr][lc4] = bf;
    __syncthreads();
#pragma unroll 4
    for (int kk = 0; kk < nr; kk++) {
      const float4 a4 = *(const float4*)&Al[kk][dm];
      const float4 b4 = *(const float4*)&Bl[kk][mm];
      const float aa[4] = {a4.x, a4.y, a4.z, a4.w};
      const float bb[4] = {b4.x, b4.y, b4.z, b4.w};
#pragma unroll
      for (int i = 0; i < 4; i++)
#pragma unroll
        for (int j = 0; j < 4; j++) acc[i][j] = fmaf(aa[i], bb[j], acc[i][j]);
    }
    __syncthreads();
  }
#pragma unroll
  for (int i = 0; i < 4; i++) {
    const int d = d0 + dm + i;
    if (d < DIN)
      *(float4*)(part + (((long)(kc * HH + h) * DIN + d) * MF + mm)) =
          make_float4(acc[i][0], acc[i][1], acc[i][2], acc[i][3]);
  }
}

// reduce split-K partials -> bf16 hi/lo lastT, padded to LTP d-rows
__global__ void reduce_last2(const float* __restrict__ part,
                             bf16* __restrict__ hi, bf16* __restrict__ lo) {
  const int d = blockIdx.x, h = blockIdx.y, m = threadIdx.x;  // (272, 4) x 64
  float s = 0.f;
  if (d < DIN) {
#pragma unroll 8
    for (int kc = 0; kc < NKC; kc++)
      s += part[(((long)(kc * HH + h) * DIN + d) * MF + m)];
  }
  const bf16 hv = (bf16)s;
  hi[((long)h * LTP + d) * MF + m] = hv;
  lo[((long)h * LTP + d) * MF + m] = (bf16)(s - (float)hv);
}

// ---------------------------------------------------------------------------
// fuse2: MFMA epilogue. 32 rows/block, 4 waves each owning a 64-col strip
// (wave 0 additionally owns the d=256..271 padded strip). z = qp @ lastT^T
// via bf16 hi+lo split (fp32 fidelity). Row stats via shfl_xor + tiny LDS.
// ---------------------------------------------------------------------------
__global__ __launch_bounds__(256) void fuse2_kernel(
    const bf16* __restrict__ qpA, const float* __restrict__ vA,
    const bf16* __restrict__ hiA, const bf16* __restrict__ loA,
    const bf16* __restrict__ qpB, const float* __restrict__ vB,
    const bf16* __restrict__ hiB, const bf16* __restrict__ loB,
    float* __restrict__ out)
{
  const int side = blockIdx.y;
  const bf16* qp = side ? qpB : qpA;
  const float* v = side ? vB : vA;
  const bf16* hi = side ? hiB : hiA;
  const bf16* lo = side ? loB : loA;
  float* o = out + (long)side * NR * DIN;

  __shared__ float rs_mn[32][4];
  __shared__ float rs_vz[32][4];
  __shared__ float z0s[32];
  __shared__ float a2s[HH][32];
  __shared__ float4 scal[32];
  __shared__ float fin[32];

  const int t = threadIdx.x;
  const int n0 = blockIdx.x * 32;
  const int w = t >> 6, lane = t & 63;
  const int m16 = lane & 15, q = lane >> 4;
  const int NJ = (w == 0) ? 5 : 4;

  if (t < 128) {
    const int h = t >> 5, row = t & 31;
    const float tv = v[((long)h * NR + n0 + row) * DIN];
    a2s[h][row] = 2.f * tv * tv - 1.f;  // sum_d v_d^2 = 2 t^2 - 1
  }
  __syncthreads();

  f32x4 macc[2][5] = {};

  for (int h = 0; h < HH; h++) {
    bf16x8 af[2][2];
#pragma unroll
    for (int i = 0; i < 2; i++)
#pragma unroll
      for (int hf = 0; hf < 2; hf++)
        af[i][hf] = *(const bf16x8*)(qp + ((long)h * NR + n0 + i * 16 + m16) * MF + hf * 32 + q * 8);

    f32x4 acc[2][5];
#pragma unroll
    for (int i = 0; i < 2; i++)
#pragma unroll
      for (int j = 0; j < 5; j++) acc[i][j] = (f32x4){0.f, 0.f, 0.f, 0.f};

    for (int j = 0; j < NJ; j++) {
      const int d = (j < 4) ? (w * 64 + j * 16 + m16) : (256 + m16);
      const bf16* ph = hi + ((long)h * LTP + d) * MF + q * 8;
      const bf16* pl = lo + ((long)h * LTP + d) * MF + q * 8;
      const bf16x8 bh0 = *(const bf16x8*)ph, bh1 = *(const bf16x8*)(ph + 32);
      const bf16x8 bl0 = *(const bf16x8*)pl, bl1 = *(const bf16x8*)(pl + 32);
#pragma unroll
      for (int i = 0; i < 2; i++) {
        f32x4 a = acc[i][j];
        a = __builtin_amdgcn_mfma_f32_16x16x32_bf16(af[i][1], bl1, a, 0, 0, 0);
        a = __builtin_amdgcn_mfma_f32_16x16x32_bf16(af[i][0], bl0, a, 0, 0, 0);
        a = __builtin_amdgcn_mfma_f32_16x16x32_bf16(af[i][1], bh1, a, 0, 0, 0);
        a = __builtin_amdgcn_mfma_f32_16x16x32_bf16(af[i][0], bh0, a, 0, 0, 0);
        acc[i][j] = a;
      }
    }

    // mnorm(z) per row (+ capture z0)
#pragma unroll
    for (int i = 0; i < 2; i++)
#pragma unroll
      for (int r = 0; r < 4; r++) {
        float s = 0.f;
        for (int j = 0; j < NJ; j++) { const float zz = acc[i][j][r]; s = fmaf(zz, zz, s); }
        if (w == 0 && m16 == 0) s -= 2.f * acc[i][0][r] * acc[i][0][r];
        s += __shfl_xor(s, 1); s += __shfl_xor(s, 2);
        s += __shfl_xor(s, 4); s += __shfl_xor(s, 8);
        if (m16 == 0) {
          rs_mn[i * 16 + q * 4 + r][w] = s;
          if (w == 0) z0s[i * 16 + q * 4 + r] = acc[i][0][r];
        }
      }
    // sum_d v*z per row
#pragma unroll
    for (int i = 0; i < 2; i++)
#pragma unroll
      for (int r = 0; r < 4; r++) {
        const float* vr = v + ((long)h * NR + n0 + i * 16 + q * 4 + r) * DIN;
        float s = 0.f;
        for (int j = 0; j < NJ; j++) {
          const int d = (j < 4) ? (w * 64 + j * 16 + m16) : (256 + m16);
          float a = 0.f;
          if (d < DIN) a = vr[d];
          s = fmaf(a, acc[i][j][r], s);
        }
        s += __shfl_xor(s, 1); s += __shfl_xor(s, 2);
        s += __shfl_xor(s, 4); s += __shfl_xor(s, 8);
        if (m16 == 0) rs_vz[i * 16 + q * 4 + r][w] = s;
      }
    __syncthreads();
    if (t < 32) {
      const float mn = rs_mn[t][0] + rs_mn[t][1] + rs_mn[t][2] + rs_mn[t][3];
      const float svz = rs_vz[t][0] + rs_vz[t][1] + rs_vz[t][2] + rs_vz[t][3];
      const float z0 = z0s[t];
      const float a2 = a2s[h][t];
      const float cf = 1.f / sqrtf(fabsf(mn + 1e-7f));
      const float ab = cf * svz;
      const float b2 = cf * cf * (mn + 2.f * z0 * z0);
      const float den = 1.f + 2.f * ab + a2 * b2;
      const float inv = 0.25f / (den + 1e-7f);
      scal[t] = make_float4((1.f + 2.f * ab + b2) * inv, (1.f - a2) * cf * inv, 0.f, 0.f);
    }
    __syncthreads();
    // mobius accumulate into macc
#pragma unroll
    for (int i = 0; i < 2; i++)
#pragma unroll
      for (int r = 0; r < 4; r++) {
        const float4 sc = scal[i * 16 + q * 4 + r];
        const float* vr = v + ((long)h * NR + n0 + i * 16 + q * 4 + r) * DIN;
        for (int j = 0; j < NJ; j++) {
          const int d = (j < 4) ? (w * 64 + j * 16 + m16) : (256 + m16);
          float a = 0.f;
          if (d < DIN) a = vr[d];
          macc[i][j][r] = fmaf(sc.x, a, fmaf(sc.y, acc[i][j][r], macc[i][j][r]));
        }
      }
    __syncthreads();
  }

  // final hyperbolic aggregate
#pragma unroll
  for (int i = 0; i < 2; i++)
#pragma unroll
    for (int r = 0; r < 4; r++) {
      float s = 0.f;
      for (int j = 0; j < NJ; j++) { const float mm = macc[i][j][r]; s = fmaf(mm, mm, s); }
      if (w == 0 && m16 == 0) s -= 2.f * macc[i][0][r] * macc[i][0][r];
      s += __shfl_xor(s, 1); s += __shfl_xor(s, 2);
      s += __shfl_xor(s, 4); s += __shfl_xor(s, 8);
      if (m16 == 0) rs_mn[i * 16 + q * 4 + r][w] = s;
    }
  __syncthreads();
  if (t < 32)
    fin[t] = 1.f / sqrtf(fabsf(rs_mn[t][0] + rs_mn[t][1] + rs_mn[t][2] + rs_mn[t][3]) + 1e-7f);
  __syncthreads();
#pragma unroll
  for (int i = 0; i < 2; i++)
#pragma unroll
    for (int r = 0; r < 4; r++) {
      const float fv = fin[i * 16 + q * 4 + r];
      float* orow = o + (long)(n0 + i * 16 + q * 4 + r) * DIN;
      for (int j = 0; j < NJ; j++) {
        const int d = (j < 4) ? (w * 64 + j * 16 + m16) : (256 + m16);
        if (d < DIN) orow[d] = macc[i][j][r] * fv;
      }
    }
}

extern "C" void kernel_launch(void* const* d_in, const int* in_sizes, int n_in,
                              void* d_out, int out_size, void* d_ws, size_t ws_size,
                              hipStream_t stream) {
  const float* u    = (const float*)d_in[0];
  const float* ii   = (const float*)d_in[1];
  const float* Wk   = (const float*)d_in[2];
  const float* bk   = (const float*)d_in[3];
  const float* Wq   = (const float*)d_in[4];
  const float* bq   = (const float*)d_in[5];
  const float* Wv   = (const float*)d_in[6];
  const float* bv   = (const float*)d_in[7];
  const float* proj = (const float*)d_in[8];
  float* out = (float*)d_out;

  const long NV = (long)HH * NR * DIN;
  const long NF = (long)HH * NR * MF;
  const long NLT = (long)HH * LTP * MF;  // 69632
  float* v_u = (float*)d_ws;
  float* v_i = v_u + NV;
  bf16* qp_u = (bf16*)(v_i + NV);
  bf16* kp_u = qp_u + NF;
  bf16* qp_i = kp_u + NF;
  bf16* kp_i = qp_i + NF;
  bf16* ltHi_u = kp_i + NF;
  bf16* ltLo_u = ltHi_u + NLT;
  bf16* ltHi_i = ltLo_u + NLT;
  bf16* ltLo_i = ltHi_i + NLT;
  bf16* xb_u  = ltLo_i + NLT;
  bf16* xb_i  = xb_u + (long)NR * KP;
  bf16* WbTq  = xb_i + (long)NR * KP;
  bf16* WbTk  = WbTq + 4 * 256 * KP;
  bf16* WbTv  = WbTk + 4 * 256 * KP;
  bf16* projT = WbTv + 4 * 256 * KP;
  float* part = (float*)xb_u;  // aliases staging (dead after projections)

  cvt_x_kernel<<<NR, KP, 0, stream>>>(u, xb_u);
  cvt_x_kernel<<<NR, KP, 0, stream>>>(ii, xb_i);
  cvt_w_kernel<<<dim3(1024, 3), KP, 0, stream>>>(Wq, Wk, Wv, WbTq, WbTk, WbTv);
  cvt_p_kernel<<<64, 256, 0, stream>>>(proj, projT);

  dim3 gp((NR + 63) / 64, HH);
  proj_kernel<0><<<gp, 256, 0, stream>>>(xb_u, WbTv, bv, nullptr, v_u, nullptr);
  proj_kernel<0><<<gp, 256, 0, stream>>>(xb_i, WbTv, bv, nullptr, v_i, nullptr);
  proj_kernel<1><<<gp, 256, 0, stream>>>(xb_u, WbTq, bq, projT, nullptr, qp_u);
  proj_kernel<1><<<gp, 256, 0, stream>>>(xb_u, WbTk, bk, projT, nullptr, kp_u);
  proj_kernel<1><<<gp, 256, 0, stream>>>(xb_i, WbTq, bq, projT, nullptr, qp_i);
  proj_kernel<1><<<gp, 256, 0, stream>>>(xb_i, WbTk, bk, projT, nullptr, kp_i);

  last_kernel<<<dim3(5, NKC, HH), 256, 0, stream>>>(v_i, kp_i, part);
  reduce_last2<<<dim3(LTP, HH), 64, 0, stream>>>(part, ltHi_u, ltLo_u);
  last_kernel<<<dim3(5, NKC, HH), 256, 0, stream>>>(v_u, kp_u, part);
  reduce_last2<<<dim3(LTP, HH), 64, 0, stream>>>(part, ltHi_i, ltLo_i);

  fuse2_kernel<<<dim3(NR / 32, 2), 256, 0, stream>>>(
      qp_u, v_u, ltHi_u, ltLo_u, qp_i, v_i, ltHi_i, ltLo_i, out);
}

// Round 4
// 690.000 us; speedup vs baseline: 1.6718x; 1.6718x over previous
//
#include <hip/hip_runtime.h>
#include <hip/hip_bf16.h>

#define HH 4
#define NR 20000
#define DIN 257
#define DS 256
#define MF 64
#define KP 288   // padded K for bf16 staging (9 chunks of 32)
#define NKC 32
#define LTP 272  // lastT padded d-rows (17 strips of 16)
#define ZST 276  // LDS z-tile row stride (floats): 2-way-max bank pattern, 16B-aligned

typedef __bf16 bf16;
typedef bf16 bf16x8 __attribute__((ext_vector_type(8)));
typedef bf16 bf16x4 __attribute__((ext_vector_type(4)));
typedef float f32x4 __attribute__((ext_vector_type(4)));

__device__ __forceinline__ void load_lds16(const void* g, void* l) {
  __builtin_amdgcn_global_load_lds((const __attribute__((address_space(1))) void*)g,
                                   (__attribute__((address_space(3))) void*)l,
                                   16, 0, 0);
}

// ---------------------------------------------------------------------------
// conversion kernels
// ---------------------------------------------------------------------------
__global__ void cvt_x_kernel(const float* __restrict__ x, bf16* __restrict__ xb) {
  const int n = blockIdx.x, k = threadIdx.x;  // 288 threads
  xb[(long)n * KP + k] = (k < DIN) ? (bf16)x[(long)n * DIN + k] : (bf16)0.f;
}

__global__ void cvt_w_kernel(const float* __restrict__ Wq, const float* __restrict__ Wk,
                             const float* __restrict__ Wv, bf16* __restrict__ WbTq,
                             bf16* __restrict__ WbTk, bf16* __restrict__ WbTv) {
  const int which = blockIdx.y;
  const int h = blockIdx.x >> 8, n = blockIdx.x & 255, k = threadIdx.x;
  const float* W = which == 0 ? Wq : (which == 1 ? Wk : Wv);
  bf16* o = which == 0 ? WbTq : (which == 1 ? WbTk : WbTv);
  o[((long)h * 256 + n) * KP + k] =
      (k < DIN) ? (bf16)W[((long)h * DIN + k) * DS + n] : (bf16)0.f;
}

__global__ void cvt_p_kernel(const float* __restrict__ proj, bf16* __restrict__ projT) {
  const int nm = blockIdx.x, k = threadIdx.x;  // 64 x 256
  projT[nm * 256 + k] = (bf16)proj[(long)k * MF + nm];
}

// ---------------------------------------------------------------------------
// MFMA projection kernel (unchanged from round 2).
// ---------------------------------------------------------------------------
template <int MODE>
__global__ __launch_bounds__(256) void proj_kernel(
    const bf16* __restrict__ xb, const bf16* __restrict__ WbT,
    const float* __restrict__ b, const bf16* __restrict__ projT,
    float* __restrict__ vout, bf16* __restrict__ fout)
{
  __shared__ __align__(16) unsigned char smem[35072];
  bf16* As = (bf16*)smem;              // [64][40]
  bf16* Bs = (bf16*)(smem + 5120);     // [4][256][8]
  bf16* Ss = (bf16*)smem;              // phase2: [64][264]
  float* rs = (float*)(smem + 33792);  // [64][4]
  float* fr = (float*)(smem + 34816);  // [64]

  const int t = threadIdx.x;
  const int h = blockIdx.y;
  const int n0 = blockIdx.x * 64;
  const int w = t >> 6, lane = t & 63;
  const int m16 = lane & 15, q = lane >> 4;

  f32x4 acc[4][4] = {};
  const bf16* wbh = WbT + (long)h * 256 * KP;

  for (int c = 0; c < 9; c++) {
    const int k0 = c * 32;
    {
      const int row = t >> 2, ko = (t & 3) * 8;
      const int rv = min(n0 + row, NR - 1);
      bf16x8 av = *(const bf16x8*)(xb + (long)rv * KP + k0 + ko);
      *(bf16x8*)(As + row * 40 + ko) = av;
    }
    {
      const bf16* gb = wbh + k0 + w * 8;
      for (int s = 0; s < 4; s++) {
        const int n = s * 64 + lane;
        load_lds16(gb + (long)n * KP, Bs + w * 2048 + s * 512);
      }
    }
    __syncthreads();
    bf16x8 af[4], bfj[4];
#pragma unroll
    for (int i = 0; i < 4; i++)
      af[i] = *(const bf16x8*)(As + (i * 16 + m16) * 40 + q * 8);
#pragma unroll
    for (int j = 0; j < 4; j++)
      bfj[j] = *(const bf16x8*)(Bs + q * 2048 + (w * 64 + j * 16 + m16) * 8);
#pragma unroll
    for (int i = 0; i < 4; i++)
#pragma unroll
      for (int j = 0; j < 4; j++)
        acc[i][j] = __builtin_amdgcn_mfma_f32_16x16x32_bf16(af[i], bfj[j], acc[i][j], 0, 0, 0);
    __syncthreads();
  }

  float bias[4];
#pragma unroll
  for (int j = 0; j < 4; j++) bias[j] = b[h * DS + w * 64 + j * 16 + m16];
#pragma unroll
  for (int i = 0; i < 4; i++)
#pragma unroll
    for (int j = 0; j < 4; j++)
#pragma unroll
      for (int r = 0; r < 4; r++) acc[i][j][r] += bias[j];

#pragma unroll
  for (int i = 0; i < 4; i++)
#pragma unroll
    for (int r = 0; r < 4; r++) {
      float s = acc[i][0][r] * acc[i][0][r] + acc[i][1][r] * acc[i][1][r] +
                acc[i][2][r] * acc[i][2][r] + acc[i][3][r] * acc[i][3][r];
      for (int off = 1; off < 16; off <<= 1) s += __shfl_xor(s, off);
      if (m16 == 0) rs[(i * 16 + q * 4 + r) * 4 + w] = s;
    }
  __syncthreads();

  if (MODE == 0) {
    if (t < 64) {
      const float ss = rs[t * 4] + rs[t * 4 + 1] + rs[t * 4 + 2] + rs[t * 4 + 3];
      if (n0 + t < NR) vout[((long)h * NR + n0 + t) * DIN] = sqrtf(1.f + ss);
    }
#pragma unroll
    for (int i = 0; i < 4; i++) {
      const int row = i * 16 + q * 4;
#pragma unroll
      for (int r = 0; r < 4; r++) {
        const int rg = n0 + row + r;
        if (rg < NR) {
          float* vo = vout + ((long)h * NR + rg) * DIN + 1 + w * 64 + m16;
          vo[0] = acc[i][0][r]; vo[16] = acc[i][1][r];
          vo[32] = acc[i][2][r]; vo[48] = acc[i][3][r];
        }
      }
    }
  } else {
    if (t < 64) {
      const float ss = rs[t * 4] + rs[t * 4 + 1] + rs[t * 4 + 2] + rs[t * 4 + 3];
      fr[t] = 0.125f * __expf(-ss) + 1e-8f;
    }
#pragma unroll
    for (int i = 0; i < 4; i++)
#pragma unroll
      for (int j = 0; j < 4; j++)
#pragma unroll
        for (int r = 0; r < 4; r++)
          Ss[(i * 16 + q * 4 + r) * 264 + w * 64 + j * 16 + m16] = (bf16)acc[i][j][r];
    __syncthreads();
    f32x4 fc[4] = {};
    const bf16* pT = projT + (w * 16 + m16) * 256 + q * 8;
#pragma unroll
    for (int s = 0; s < 8; s++) {
      bf16x8 pb = *(const bf16x8*)(pT + s * 32);
#pragma unroll
      for (int i = 0; i < 4; i++) {
        bf16x8 sa = *(const bf16x8*)(Ss + (i * 16 + m16) * 264 + s * 32 + q * 8);
        fc[i] = __builtin_amdgcn_mfma_f32_16x16x32_bf16(sa, pb, fc[i], 0, 0, 0);
      }
    }
    const float SQ2 = 1.41421356237309515f;
#pragma unroll
    for (int i = 0; i < 4; i++) {
      const int row = i * 16 + q * 4;
#pragma unroll
      for (int r = 0; r < 4; r++) {
        const int rg = n0 + row + r;
        if (rg < NR)
          fout[((long)h * NR + rg) * MF + w * 16 + m16] =
              (bf16)(__expf(SQ2 * fc[i][r]) * fr[row + r]);
      }
    }
  }
}

// ---------------------------------------------------------------------------
// lastT split-K partials (unchanged)
// ---------------------------------------------------------------------------
__global__ __launch_bounds__(256) void last_kernel(
    const float* __restrict__ v, const bf16* __restrict__ f,
    float* __restrict__ part)
{
  __shared__ __align__(16) float Al[16][68];
  __shared__ __align__(16) float Bl[16][64];
  const int t = threadIdx.x;
  const int dt = blockIdx.x, kc = blockIdx.y, h = blockIdx.z;
  const int d0 = dt * 64;
  const int nbeg = kc * 625, nend = nbeg + 625;
  const int lr = t >> 4, lc4 = (t & 15) * 4;
  const int dm = (t & 15) * 4, mm = (t >> 4) * 4;
  float acc[4][4];
#pragma unroll
  for (int i = 0; i < 4; i++)
#pragma unroll
    for (int j = 0; j < 4; j++) acc[i][j] = 0.f;

  for (int n0 = nbeg; n0 < nend; n0 += 16) {
    const int nr = min(16, nend - n0);
    float av[4] = {0.f, 0.f, 0.f, 0.f};
    float4 bf = make_float4(0.f, 0.f, 0.f, 0.f);
    if (lr < nr) {
      const float* src = v + ((long)h * NR + n0 + lr) * DIN + d0 + lc4;
#pragma unroll
      for (int j = 0; j < 4; j++) av[j] = (d0 + lc4 + j < DIN) ? src[j] : 0.f;
      bf16x4 b4 = *(const bf16x4*)(f + ((long)h * NR + n0 + lr) * MF + lc4);
      bf = make_float4((float)b4[0], (float)b4[1], (float)b4[2], (float)b4[3]);
    }
    *(float4*)&Al[lr][lc4] = make_float4(av[0], av[1], av[2], av[3]);
    *(float4*)&Bl[lr][lc4] = bf;
    __syncthreads();
#pragma unroll 4
    for (int kk = 0; kk < nr; kk++) {
      const float4 a4 = *(const float4*)&Al[kk][dm];
      const float4 b4 = *(const float4*)&Bl[kk][mm];
      const float aa[4] = {a4.x, a4.y, a4.z, a4.w};
      const float bb[4] = {b4.x, b4.y, b4.z, b4.w};
#pragma unroll
      for (int i = 0; i < 4; i++)
#pragma unroll
        for (int j = 0; j < 4; j++) acc[i][j] = fmaf(aa[i], bb[j], acc[i][j]);
    }
    __syncthreads();
  }
#pragma unroll
  for (int i = 0; i < 4; i++) {
    const int d = d0 + dm + i;
    if (d < DIN)
      *(float4*)(part + (((long)(kc * HH + h) * DIN + d) * MF + mm)) =
          make_float4(acc[i][0], acc[i][1], acc[i][2], acc[i][3]);
  }
}

// reduce split-K partials -> bf16 hi/lo lastT, padded to LTP d-rows
__global__ void reduce_last2(const float* __restrict__ part,
                             bf16* __restrict__ hi, bf16* __restrict__ lo) {
  const int d = blockIdx.x, h = blockIdx.y, m = threadIdx.x;  // (272, 4) x 64
  float s = 0.f;
  if (d < DIN) {
#pragma unroll 8
    for (int kc = 0; kc < NKC; kc++)
      s += part[(((long)(kc * HH + h) * DIN + d) * MF + m)];
  }
  const bf16 hv = (bf16)s;
  hi[((long)h * LTP + d) * MF + m] = hv;
  lo[((long)h * LTP + d) * MF + m] = (bf16)(s - (float)hv);
}

// ---------------------------------------------------------------------------
// fuse3: MFMA z -> LDS transpose -> row-contiguous epilogue.
// 32 rows/block, 256 thr. Phase 1: wave w computes d-tiles {w,w+4,w+8,w+12}
// (+tile 16 for w0) of z = qp @ lastT^T (bf16 hi+lo, fp32 fidelity), writes
// row-major into zs[32][ZST]. Phase 2: thread (t>>3=row, t&7=colgrp) holds
// z,v as 8 float4 regs; stats via 3 shfl_xor in the 8-lane row group.
// v is read exactly once per element (loads issued before the barrier).
// ---------------------------------------------------------------------------
__global__ __launch_bounds__(256) void fuse3_kernel(
    const bf16* __restrict__ qpA, const float* __restrict__ vA,
    const bf16* __restrict__ hiA, const bf16* __restrict__ loA,
    const bf16* __restrict__ qpB, const float* __restrict__ vB,
    const bf16* __restrict__ hiB, const bf16* __restrict__ loB,
    float* __restrict__ out)
{
  __shared__ __align__(16) float zs[32 * ZST];

  const int side = blockIdx.y;
  const bf16* qp = side ? qpB : qpA;
  const float* v = side ? vB : vA;
  const bf16* hi = side ? hiB : hiA;
  const bf16* lo = side ? loB : loA;
  float* o = out + (long)side * NR * DIN;

  const int t = threadIdx.x;
  const int n0 = blockIdx.x * 32;
  const int w = t >> 6, lane = t & 63;
  const int m16 = lane & 15, q = lane >> 4;
  const int erow = t >> 3, ecol = (t & 7) * 4;
  const bool lead = ((t & 7) == 0);
  const int ntile = (w == 0) ? 5 : 4;

  f32x4 macc[8] = {};
  float macc256 = 0.f;

  for (int h = 0; h < HH; h++) {
    // ---- v loads issued first: overlap with MFMA phase (no barrier between)
    const float* vr = v + ((long)h * NR + n0 + erow) * DIN;
    f32x4 vreg[8];
#pragma unroll
    for (int it = 0; it < 8; it++)
      vreg[it] = *(const f32x4*)(vr + it * 32 + ecol);
    float v256 = lead ? vr[256] : 0.f;

    // ---- phase 1: z tiles
    bf16x8 af[2][2];
#pragma unroll
    for (int i = 0; i < 2; i++)
#pragma unroll
      for (int hf = 0; hf < 2; hf++)
        af[i][hf] = *(const bf16x8*)(qp + ((long)h * NR + n0 + i * 16 + m16) * MF + hf * 32 + q * 8);

    for (int jt = 0; jt < ntile; jt++) {
      const int dt = (jt < 4) ? (w + jt * 4) : 16;
      const int d = dt * 16 + m16;
      const bf16* ph = hi + ((long)h * LTP + d) * MF + q * 8;
      const bf16* pl = lo + ((long)h * LTP + d) * MF + q * 8;
      const bf16x8 bh0 = *(const bf16x8*)ph, bh1 = *(const bf16x8*)(ph + 32);
      const bf16x8 bl0 = *(const bf16x8*)pl, bl1 = *(const bf16x8*)(pl + 32);
#pragma unroll
      for (int i = 0; i < 2; i++) {
        f32x4 a = {0.f, 0.f, 0.f, 0.f};
        a = __builtin_amdgcn_mfma_f32_16x16x32_bf16(af[i][1], bl1, a, 0, 0, 0);
        a = __builtin_amdgcn_mfma_f32_16x16x32_bf16(af[i][0], bl0, a, 0, 0, 0);
        a = __builtin_amdgcn_mfma_f32_16x16x32_bf16(af[i][1], bh1, a, 0, 0, 0);
        a = __builtin_amdgcn_mfma_f32_16x16x32_bf16(af[i][0], bh0, a, 0, 0, 0);
#pragma unroll
        for (int r = 0; r < 4; r++)
          zs[(i * 16 + q * 4 + r) * ZST + d] = a[r];
      }
    }
    __syncthreads();

    // ---- phase 2: row-contiguous epilogue
    f32x4 zreg[8];
    float sz2 = 0.f, svz = 0.f, z0p = 0.f, v02p = 0.f;
#pragma unroll
    for (int it = 0; it < 8; it++) {
      zreg[it] = *(const f32x4*)&zs[erow * ZST + it * 32 + ecol];
#pragma unroll
      for (int c = 0; c < 4; c++) {
        sz2 = fmaf(zreg[it][c], zreg[it][c], sz2);
        svz = fmaf(vreg[it][c], zreg[it][c], svz);
      }
    }
    float z256 = 0.f;
    if (lead) {
      z256 = zs[erow * ZST + 256];
      sz2 = fmaf(z256, z256, sz2);
      svz = fmaf(v256, z256, svz);
      z0p = zreg[0][0];
      v02p = vreg[0][0] * vreg[0][0];
    }
#pragma unroll
    for (int off = 1; off < 8; off <<= 1) {
      sz2 += __shfl_xor(sz2, off);
      svz += __shfl_xor(svz, off);
      z0p += __shfl_xor(z0p, off);
      v02p += __shfl_xor(v02p, off);
    }
    const float a2 = 2.f * v02p - 1.f;           // sum v^2 = 2 t^2 - 1
    const float mn = sz2 - 2.f * z0p * z0p;      // mnorm(z)
    const float cf = 1.f / sqrtf(fabsf(mn + 1e-7f));
    const float ab = cf * svz;
    const float b2 = cf * cf * sz2;
    const float den = 1.f + 2.f * ab + a2 * b2;
    const float inv = 0.25f / (den + 1e-7f);
    const float sx = (1.f + 2.f * ab + b2) * inv;
    const float sy = (1.f - a2) * cf * inv;
#pragma unroll
    for (int it = 0; it < 8; it++)
#pragma unroll
      for (int c = 0; c < 4; c++)
        macc[it][c] = fmaf(sx, vreg[it][c], fmaf(sy, zreg[it][c], macc[it][c]));
    if (lead) macc256 = fmaf(sx, v256, fmaf(sy, z256, macc256));
    __syncthreads();  // zs reused next head
  }

  // ---- final hyperbolic aggregate
  float sm2 = 0.f, m02p = 0.f;
#pragma unroll
  for (int it = 0; it < 8; it++)
#pragma unroll
    for (int c = 0; c < 4; c++) sm2 = fmaf(macc[it][c], macc[it][c], sm2);
  if (lead) {
    sm2 = fmaf(macc256, macc256, sm2);
    m02p = macc[0][0] * macc[0][0];
  }
#pragma unroll
  for (int off = 1; off < 8; off <<= 1) {
    sm2 += __shfl_xor(sm2, off);
    m02p += __shfl_xor(m02p, off);
  }
  const float fv = 1.f / sqrtf(fabsf(sm2 - 2.f * m02p) + 1e-7f);
  float* orow = o + (long)(n0 + erow) * DIN;
#pragma unroll
  for (int it = 0; it < 8; it++)
#pragma unroll
    for (int c = 0; c < 4; c++) orow[it * 32 + ecol + c] = macc[it][c] * fv;
  if (lead) orow[256] = macc256 * fv;
}

extern "C" void kernel_launch(void* const* d_in, const int* in_sizes, int n_in,
                              void* d_out, int out_size, void* d_ws, size_t ws_size,
                              hipStream_t stream) {
  const float* u    = (const float*)d_in[0];
  const float* ii   = (const float*)d_in[1];
  const float* Wk   = (const float*)d_in[2];
  const float* bk   = (const float*)d_in[3];
  const float* Wq   = (const float*)d_in[4];
  const float* bq   = (const float*)d_in[5];
  const float* Wv   = (const float*)d_in[6];
  const float* bv   = (const float*)d_in[7];
  const float* proj = (const float*)d_in[8];
  float* out = (float*)d_out;

  const long NV = (long)HH * NR * DIN;
  const long NF = (long)HH * NR * MF;
  const long NLT = (long)HH * LTP * MF;  // 69632
  float* v_u = (float*)d_ws;
  float* v_i = v_u + NV;
  bf16* qp_u = (bf16*)(v_i + NV);
  bf16* kp_u = qp_u + NF;
  bf16* qp_i = kp_u + NF;
  bf16* kp_i = qp_i + NF;
  bf16* ltHi_u = kp_i + NF;
  bf16* ltLo_u = ltHi_u + NLT;
  bf16* ltHi_i = ltLo_u + NLT;
  bf16* ltLo_i = ltHi_i + NLT;
  bf16* xb_u  = ltLo_i + NLT;
  bf16* xb_i  = xb_u + (long)NR * KP;
  bf16* WbTq  = xb_i + (long)NR * KP;
  bf16* WbTk  = WbTq + 4 * 256 * KP;
  bf16* WbTv  = WbTk + 4 * 256 * KP;
  bf16* projT = WbTv + 4 * 256 * KP;
  float* part = (float*)xb_u;  // aliases staging (dead after projections)

  cvt_x_kernel<<<NR, KP, 0, stream>>>(u, xb_u);
  cvt_x_kernel<<<NR, KP, 0, stream>>>(ii, xb_i);
  cvt_w_kernel<<<dim3(1024, 3), KP, 0, stream>>>(Wq, Wk, Wv, WbTq, WbTk, WbTv);
  cvt_p_kernel<<<64, 256, 0, stream>>>(proj, projT);

  dim3 gp((NR + 63) / 64, HH);
  proj_kernel<0><<<gp, 256, 0, stream>>>(xb_u, WbTv, bv, nullptr, v_u, nullptr);
  proj_kernel<0><<<gp, 256, 0, stream>>>(xb_i, WbTv, bv, nullptr, v_i, nullptr);
  proj_kernel<1><<<gp, 256, 0, stream>>>(xb_u, WbTq, bq, projT, nullptr, qp_u);
  proj_kernel<1><<<gp, 256, 0, stream>>>(xb_u, WbTk, bk, projT, nullptr, kp_u);
  proj_kernel<1><<<gp, 256, 0, stream>>>(xb_i, WbTq, bq, projT, nullptr, qp_i);
  proj_kernel<1><<<gp, 256, 0, stream>>>(xb_i, WbTk, bk, projT, nullptr, kp_i);

  last_kernel<<<dim3(5, NKC, HH), 256, 0, stream>>>(v_i, kp_i, part);
  reduce_last2<<<dim3(LTP, HH), 64, 0, stream>>>(part, ltHi_u, ltLo_u);
  last_kernel<<<dim3(5, NKC, HH), 256, 0, stream>>>(v_u, kp_u, part);
  reduce_last2<<<dim3(LTP, HH), 64, 0, stream>>>(part, ltHi_i, ltLo_i);

  fuse3_kernel<<<dim3(NR / 32, 2), 256, 0, stream>>>(
      qp_u, v_u, ltHi_u, ltLo_u, qp_i, v_i, ltHi_i, ltLo_i, out);
}

// Round 5
// 653.656 us; speedup vs baseline: 1.7647x; 1.0556x over previous
//
#include <hip/hip_runtime.h>
#include <hip/hip_bf16.h>

#define HH 4
#define NR 20000
#define DIN 257
#define DS 256
#define MF 64
#define KP 288   // padded K for bf16 staging (9 chunks of 32)
#define LTP 272  // lastT padded d-rows
#define ZST 276  // fuse3 LDS z-tile row stride
#define LKC 25   // last3: split-K grid dim AND chunks/block (25*25*32 = 20000)

typedef __bf16 bf16;
typedef bf16 bf16x8 __attribute__((ext_vector_type(8)));
typedef bf16 bf16x4 __attribute__((ext_vector_type(4)));
typedef bf16 bf16x2 __attribute__((ext_vector_type(2)));
typedef float f32x4 __attribute__((ext_vector_type(4)));
typedef unsigned int u32x4 __attribute__((ext_vector_type(4)));

__device__ __forceinline__ void load_lds16(const void* g, void* l) {
  __builtin_amdgcn_global_load_lds((const __attribute__((address_space(1))) void*)g,
                                   (__attribute__((address_space(3))) void*)l,
                                   16, 0, 0);
}

// ---------------------------------------------------------------------------
// conversion kernels
// ---------------------------------------------------------------------------
__global__ void cvt_x_kernel(const float* __restrict__ x, bf16* __restrict__ xb) {
  const int n = blockIdx.x, k = threadIdx.x;  // 288 threads
  xb[(long)n * KP + k] = (k < DIN) ? (bf16)x[(long)n * DIN + k] : (bf16)0.f;
}

__global__ void cvt_w_kernel(const float* __restrict__ Wq, const float* __restrict__ Wk,
                             const float* __restrict__ Wv, bf16* __restrict__ WbTq,
                             bf16* __restrict__ WbTk, bf16* __restrict__ WbTv) {
  const int which = blockIdx.y;
  const int h = blockIdx.x >> 8, n = blockIdx.x & 255, k = threadIdx.x;
  const float* W = which == 0 ? Wq : (which == 1 ? Wk : Wv);
  bf16* o = which == 0 ? WbTq : (which == 1 ? WbTk : WbTv);
  o[((long)h * 256 + n) * KP + k] =
      (k < DIN) ? (bf16)W[((long)h * DIN + k) * DS + n] : (bf16)0.f;
}

__global__ void cvt_p_kernel(const float* __restrict__ proj, bf16* __restrict__ projT) {
  const int nm = blockIdx.x, k = threadIdx.x;  // 64 x 256
  projT[nm * 256 + k] = (bf16)proj[(long)k * MF + nm];
}

// ---------------------------------------------------------------------------
// value2: merged value projection, 128-row tiles. grid (157, 4, 2).
// ---------------------------------------------------------------------------
__global__ __launch_bounds__(256) void value2_kernel(
    const bf16* __restrict__ xbA, const bf16* __restrict__ xbB,
    const bf16* __restrict__ WbT, const float* __restrict__ b,
    float* __restrict__ voA, float* __restrict__ voB)
{
  __shared__ __align__(16) unsigned char smem[28672];
  bf16* As = (bf16*)smem;              // [128][40] = 10240 B
  bf16* Bs = (bf16*)(smem + 10240);    // [4][256][8] = 16384 B
  float* rs = (float*)(smem + 26624);  // [128][4]

  const int t = threadIdx.x;
  const int h = blockIdx.y;
  const int n0 = blockIdx.x * 128;
  const bf16* xb = blockIdx.z ? xbB : xbA;
  float* vout = blockIdx.z ? voB : voA;
  const int w = t >> 6, lane = t & 63;
  const int m16 = lane & 15, q = lane >> 4;

  f32x4 acc[8][4] = {};
  const bf16* wbh = WbT + (long)h * 256 * KP;

  for (int c = 0; c < 9; c++) {
    const int k0 = c * 32;
    {
      const int row = t >> 1, ko = (t & 1) * 16;
      const int rv = min(n0 + row, NR - 1);
      const bf16* src = xb + (long)rv * KP + k0 + ko;
      *(bf16x8*)(As + row * 40 + ko) = *(const bf16x8*)src;
      *(bf16x8*)(As + row * 40 + ko + 8) = *(const bf16x8*)(src + 8);
    }
    {
      const bf16* gb = wbh + k0 + w * 8;
      for (int s = 0; s < 4; s++)
        load_lds16(gb + (long)(s * 64 + lane) * KP, Bs + w * 2048 + s * 512);
    }
    __syncthreads();
    bf16x8 af[8], bfj[4];
#pragma unroll
    for (int i = 0; i < 8; i++)
      af[i] = *(const bf16x8*)(As + (i * 16 + m16) * 40 + q * 8);
#pragma unroll
    for (int j = 0; j < 4; j++)
      bfj[j] = *(const bf16x8*)(Bs + q * 2048 + (w * 64 + j * 16 + m16) * 8);
#pragma unroll
    for (int i = 0; i < 8; i++)
#pragma unroll
      for (int j = 0; j < 4; j++)
        acc[i][j] = __builtin_amdgcn_mfma_f32_16x16x32_bf16(af[i], bfj[j], acc[i][j], 0, 0, 0);
    __syncthreads();
  }

  float bias[4];
#pragma unroll
  for (int j = 0; j < 4; j++) bias[j] = b[h * DS + w * 64 + j * 16 + m16];
#pragma unroll
  for (int i = 0; i < 8; i++)
#pragma unroll
    for (int r = 0; r < 4; r++) {
      float s = 0.f;
#pragma unroll
      for (int j = 0; j < 4; j++) {
        acc[i][j][r] += bias[j];
        s = fmaf(acc[i][j][r], acc[i][j][r], s);
      }
      for (int off = 1; off < 16; off <<= 1) s += __shfl_xor(s, off);
      if (m16 == 0) rs[(i * 16 + q * 4 + r) * 4 + w] = s;
    }
  __syncthreads();
  if (t < 128) {
    const float ss = rs[t * 4] + rs[t * 4 + 1] + rs[t * 4 + 2] + rs[t * 4 + 3];
    if (n0 + t < NR) vout[((long)h * NR + n0 + t) * DIN] = sqrtf(1.f + ss);
  }
#pragma unroll
  for (int i = 0; i < 8; i++) {
    const int row = i * 16 + q * 4;
#pragma unroll
    for (int r = 0; r < 4; r++) {
      const int rg = n0 + row + r;
      if (rg < NR) {
        float* vo = vout + ((long)h * NR + rg) * DIN + 1 + w * 64 + m16;
        vo[0] = acc[i][0][r]; vo[16] = acc[i][1][r];
        vo[32] = acc[i][2][r]; vo[48] = acc[i][3][r];
      }
    }
  }
}

// ---------------------------------------------------------------------------
// qk2: merged q/k projection + feature map, 128-row tiles. grid (157, 4, 4).
// z: 0=(A,Wq->qpA) 1=(A,Wk->kpA) 2=(B,Wq->qpB) 3=(B,Wk->kpB)
// ---------------------------------------------------------------------------
__global__ __launch_bounds__(256) void qk2_kernel(
    const bf16* __restrict__ xbA, const bf16* __restrict__ xbB,
    const bf16* __restrict__ WbTq, const bf16* __restrict__ WbTk,
    const float* __restrict__ bq, const float* __restrict__ bk,
    const bf16* __restrict__ projT,
    bf16* __restrict__ qpA, bf16* __restrict__ kpA,
    bf16* __restrict__ qpB, bf16* __restrict__ kpB)
{
  __shared__ __align__(16) unsigned char smem[70144];
  bf16* As = (bf16*)smem;              // [128][40]
  bf16* Bs = (bf16*)(smem + 10240);    // 16384
  bf16* Ss = (bf16*)smem;              // phase2: [128][264] = 67584 (aliases A/B)
  float* rs = (float*)(smem + 67584);  // [128][4]
  float* fr = (float*)(smem + 69632);  // [128]

  const int t = threadIdx.x;
  const int h = blockIdx.y;
  const int z = blockIdx.z;
  const int n0 = blockIdx.x * 128;
  const bf16* xb = (z & 2) ? xbB : xbA;
  const bf16* WbT = (z & 1) ? WbTk : WbTq;
  const float* b = (z & 1) ? bk : bq;
  bf16* fout = (z == 0) ? qpA : (z == 1) ? kpA : (z == 2) ? qpB : kpB;
  const int w = t >> 6, lane = t & 63;
  const int m16 = lane & 15, q = lane >> 4;

  f32x4 acc[8][4] = {};
  const bf16* wbh = WbT + (long)h * 256 * KP;

  for (int c = 0; c < 9; c++) {
    const int k0 = c * 32;
    {
      const int row = t >> 1, ko = (t & 1) * 16;
      const int rv = min(n0 + row, NR - 1);
      const bf16* src = xb + (long)rv * KP + k0 + ko;
      *(bf16x8*)(As + row * 40 + ko) = *(const bf16x8*)src;
      *(bf16x8*)(As + row * 40 + ko + 8) = *(const bf16x8*)(src + 8);
    }
    {
      const bf16* gb = wbh + k0 + w * 8;
      for (int s = 0; s < 4; s++)
        load_lds16(gb + (long)(s * 64 + lane) * KP, Bs + w * 2048 + s * 512);
    }
    __syncthreads();
    bf16x8 af[8], bfj[4];
#pragma unroll
    for (int i = 0; i < 8; i++)
      af[i] = *(const bf16x8*)(As + (i * 16 + m16) * 40 + q * 8);
#pragma unroll
    for (int j = 0; j < 4; j++)
      bfj[j] = *(const bf16x8*)(Bs + q * 2048 + (w * 64 + j * 16 + m16) * 8);
#pragma unroll
    for (int i = 0; i < 8; i++)
#pragma unroll
      for (int j = 0; j < 4; j++)
        acc[i][j] = __builtin_amdgcn_mfma_f32_16x16x32_bf16(af[i], bfj[j], acc[i][j], 0, 0, 0);
    __syncthreads();
  }

  float bias[4];
#pragma unroll
  for (int j = 0; j < 4; j++) bias[j] = b[h * DS + w * 64 + j * 16 + m16];
#pragma unroll
  for (int i = 0; i < 8; i++)
#pragma unroll
    for (int r = 0; r < 4; r++) {
      float s = 0.f;
#pragma unroll
      for (int j = 0; j < 4; j++) {
        acc[i][j][r] += bias[j];
        s = fmaf(acc[i][j][r], acc[i][j][r], s);
      }
      for (int off = 1; off < 16; off <<= 1) s += __shfl_xor(s, off);
      if (m16 == 0) rs[(i * 16 + q * 4 + r) * 4 + w] = s;
    }
  __syncthreads();
  if (t < 128) {
    const float ss = rs[t * 4] + rs[t * 4 + 1] + rs[t * 4 + 2] + rs[t * 4 + 3];
    fr[t] = 0.125f * __expf(-ss) + 1e-8f;  // exp(1 - t^2)*m + eps
  }
  // stash full 128-row space tile into Ss (aliases A/B; GEMM done)
#pragma unroll
  for (int i = 0; i < 8; i++)
#pragma unroll
    for (int j = 0; j < 4; j++)
#pragma unroll
      for (int r = 0; r < 4; r++)
        Ss[(i * 16 + q * 4 + r) * 264 + w * 64 + j * 16 + m16] = (bf16)acc[i][j][r];
  __syncthreads();
  // feature GEMM: (128 x 256) @ projT^T -> 128 x 64; wave w = m-cols w*16..
  f32x4 fc[8] = {};
  const bf16* pT = projT + (w * 16 + m16) * 256 + q * 8;
#pragma unroll
  for (int s = 0; s < 8; s++) {
    const bf16x8 pb = *(const bf16x8*)(pT + s * 32);
#pragma unroll
    for (int i = 0; i < 8; i++) {
      const bf16x8 sa = *(const bf16x8*)(Ss + (i * 16 + m16) * 264 + s * 32 + q * 8);
      fc[i] = __builtin_amdgcn_mfma_f32_16x16x32_bf16(sa, pb, fc[i], 0, 0, 0);
    }
  }
  const float SQ2 = 1.41421356237309515f;  // 1/sqrt(tau)
#pragma unroll
  for (int i = 0; i < 8; i++) {
    const int row = i * 16 + q * 4;
#pragma unroll
    for (int r = 0; r < 4; r++) {
      const int rg = n0 + row + r;
      if (rg < NR)
        fout[((long)h * NR + rg) * MF + w * 16 + m16] =
            (bf16)(__expf(SQ2 * fc[i][r]) * fr[row + r]);
    }
  }
}

// ---------------------------------------------------------------------------
// last3: MFMA lastT[d][m] = sum_n v[n][d]*f[n][m]. grid (5, 25, 8).
// Register pair-pack transpose: thread loads rows (2np, 2np+1), packs bf16
// pairs into dwords at LDS[row=d or m][np], stride 17 dwords (conflict-free).
// Wave w: m-strip w*16; A-tiles i=0..3 over 64 d. Split-K partials fp32.
// ---------------------------------------------------------------------------
__global__ __launch_bounds__(256) void last3_kernel(
    const float* __restrict__ vA, const bf16* __restrict__ fA,
    const float* __restrict__ vB, const bf16* __restrict__ fB,
    float* __restrict__ part)
{
  __shared__ unsigned int Va[64 * 17];
  __shared__ unsigned int Fa[64 * 17];
  const int t = threadIdx.x;
  const int dt = blockIdx.x, kc = blockIdx.y, z = blockIdx.z;
  const int side = z >> 2, h = z & 3;
  const float* v = side ? vB : vA;
  const bf16* f = side ? fB : fA;
  const int d0 = dt * 64;
  const int w = t >> 6, lane = t & 63;
  const int m16 = lane & 15, q = lane >> 4;
  const int np = t >> 4, xg = (t & 15) * 4;
  f32x4 acc[4] = {};

  for (int c = 0; c < LKC; c++) {
    const int n0 = (kc * LKC + c) * 32;
    {  // V stage: 32n x 64d -> Va[d][np] packed pairs
      const float* s0 = v + ((long)h * NR + n0 + 2 * np) * DIN + d0 + xg;
      const float* s1 = s0 + DIN;
      if (d0 + xg + 3 < DIN) {
        const f32x4 a0 = *(const f32x4*)s0;
        const f32x4 a1 = *(const f32x4*)s1;
#pragma unroll
        for (int e = 0; e < 4; e++) {
          bf16x2 p; p[0] = (bf16)a0[e]; p[1] = (bf16)a1[e];
          Va[(xg + e) * 17 + np] = __builtin_bit_cast(unsigned int, p);
        }
      } else {
#pragma unroll
        for (int e = 0; e < 4; e++) {
          float a0 = 0.f, a1 = 0.f;
          if (d0 + xg + e < DIN) { a0 = s0[e]; a1 = s1[e]; }
          bf16x2 p; p[0] = (bf16)a0; p[1] = (bf16)a1;
          Va[(xg + e) * 17 + np] = __builtin_bit_cast(unsigned int, p);
        }
      }
    }
    {  // F stage: 32n x 64m -> Fa[m][np] packed pairs
      const bf16* s0 = f + ((long)h * NR + n0 + 2 * np) * MF + xg;
      const bf16x4 f0 = *(const bf16x4*)s0;
      const bf16x4 f1 = *(const bf16x4*)(s0 + MF);
#pragma unroll
      for (int e = 0; e < 4; e++) {
        bf16x2 p; p[0] = f0[e]; p[1] = f1[e];
        Fa[(xg + e) * 17 + np] = __builtin_bit_cast(unsigned int, p);
      }
    }
    __syncthreads();
    u32x4 bw;
#pragma unroll
    for (int c4 = 0; c4 < 4; c4++) bw[c4] = Fa[(w * 16 + m16) * 17 + q * 4 + c4];
    const bf16x8 bv = __builtin_bit_cast(bf16x8, bw);
#pragma unroll
    for (int i = 0; i < 4; i++) {
      u32x4 aw;
#pragma unroll
      for (int c4 = 0; c4 < 4; c4++) aw[c4] = Va[(i * 16 + m16) * 17 + q * 4 + c4];
      acc[i] = __builtin_amdgcn_mfma_f32_16x16x32_bf16(
          __builtin_bit_cast(bf16x8, aw), bv, acc[i], 0, 0, 0);
    }
    __syncthreads();
  }
  float* pp = part + ((long)(z * LKC + kc) * 5 + dt) * 4096;
#pragma unroll
  for (int i = 0; i < 4; i++)
#pragma unroll
    for (int r = 0; r < 4; r++)
      pp[(i * 16 + q * 4 + r) * 64 + w * 16 + m16] = acc[i][r];
}

// reduce split-K partials -> bf16 hi/lo lastT [h][LTP][MF], per side
__global__ void reduce_last4(const float* __restrict__ part,
                             bf16* __restrict__ hiU, bf16* __restrict__ loU,
                             bf16* __restrict__ hiI, bf16* __restrict__ loI) {
  const int d = blockIdx.x, zz = blockIdx.y, m = threadIdx.x;  // (272, 8) x 64
  const int side = zz >> 2, h = zz & 3;
  const int dt = d >> 6, dl = d & 63;
  float s = 0.f;
#pragma unroll 5
  for (int kc = 0; kc < LKC; kc++)
    s += part[((long)(zz * LKC + kc) * 5 + dt) * 4096 + dl * 64 + m];
  bf16* hi = side ? hiI : hiU;
  bf16* lo = side ? loI : loU;
  const bf16 hv = (bf16)s;
  hi[((long)h * LTP + d) * MF + m] = hv;
  lo[((long)h * LTP + d) * MF + m] = (bf16)(s - (float)hv);
}

// ---------------------------------------------------------------------------
// fuse3 (unchanged from round 4)
// ---------------------------------------------------------------------------
__global__ __launch_bounds__(256) void fuse3_kernel(
    const bf16* __restrict__ qpA, const float* __restrict__ vA,
    const bf16* __restrict__ hiA, const bf16* __restrict__ loA,
    const bf16* __restrict__ qpB, const float* __restrict__ vB,
    const bf16* __restrict__ hiB, const bf16* __restrict__ loB,
    float* __restrict__ out)
{
  __shared__ __align__(16) float zs[32 * ZST];

  const int side = blockIdx.y;
  const bf16* qp = side ? qpB : qpA;
  const float* v = side ? vB : vA;
  const bf16* hi = side ? hiB : hiA;
  const bf16* lo = side ? loB : loA;
  float* o = out + (long)side * NR * DIN;

  const int t = threadIdx.x;
  const int n0 = blockIdx.x * 32;
  const int w = t >> 6, lane = t & 63;
  const int m16 = lane & 15, q = lane >> 4;
  const int erow = t >> 3, ecol = (t & 7) * 4;
  const bool lead = ((t & 7) == 0);
  const int ntile = (w == 0) ? 5 : 4;

  f32x4 macc[8] = {};
  float macc256 = 0.f;

  for (int h = 0; h < HH; h++) {
    const float* vr = v + ((long)h * NR + n0 + erow) * DIN;
    f32x4 vreg[8];
#pragma unroll
    for (int it = 0; it < 8; it++)
      vreg[it] = *(const f32x4*)(vr + it * 32 + ecol);
    float v256 = lead ? vr[256] : 0.f;

    bf16x8 af[2][2];
#pragma unroll
    for (int i = 0; i < 2; i++)
#pragma unroll
      for (int hf = 0; hf < 2; hf++)
        af[i][hf] = *(const bf16x8*)(qp + ((long)h * NR + n0 + i * 16 + m16) * MF + hf * 32 + q * 8);

    for (int jt = 0; jt < ntile; jt++) {
      const int dt = (jt < 4) ? (w + jt * 4) : 16;
      const int d = dt * 16 + m16;
      const bf16* ph = hi + ((long)h * LTP + d) * MF + q * 8;
      const bf16* pl = lo + ((long)h * LTP + d) * MF + q * 8;
      const bf16x8 bh0 = *(const bf16x8*)ph, bh1 = *(const bf16x8*)(ph + 32);
      const bf16x8 bl0 = *(const bf16x8*)pl, bl1 = *(const bf16x8*)(pl + 32);
#pragma unroll
      for (int i = 0; i < 2; i++) {
        f32x4 a = {0.f, 0.f, 0.f, 0.f};
        a = __builtin_amdgcn_mfma_f32_16x16x32_bf16(af[i][1], bl1, a, 0, 0, 0);
        a = __builtin_amdgcn_mfma_f32_16x16x32_bf16(af[i][0], bl0, a, 0, 0, 0);
        a = __builtin_amdgcn_mfma_f32_16x16x32_bf16(af[i][1], bh1, a, 0, 0, 0);
        a = __builtin_amdgcn_mfma_f32_16x16x32_bf16(af[i][0], bh0, a, 0, 0, 0);
#pragma unroll
        for (int r = 0; r < 4; r++)
          zs[(i * 16 + q * 4 + r) * ZST + d] = a[r];
      }
    }
    __syncthreads();

    f32x4 zreg[8];
    float sz2 = 0.f, svz = 0.f, z0p = 0.f, v02p = 0.f;
#pragma unroll
    for (int it = 0; it < 8; it++) {
      zreg[it] = *(const f32x4*)&zs[erow * ZST + it * 32 + ecol];
#pragma unroll
      for (int c = 0; c < 4; c++) {
        sz2 = fmaf(zreg[it][c], zreg[it][c], sz2);
        svz = fmaf(vreg[it][c], zreg[it][c], svz);
      }
    }
    float z256 = 0.f;
    if (lead) {
      z256 = zs[erow * ZST + 256];
      sz2 = fmaf(z256, z256, sz2);
      svz = fmaf(v256, z256, svz);
      z0p = zreg[0][0];
      v02p = vreg[0][0] * vreg[0][0];
    }
#pragma unroll
    for (int off = 1; off < 8; off <<= 1) {
      sz2 += __shfl_xor(sz2, off);
      svz += __shfl_xor(svz, off);
      z0p += __shfl_xor(z0p, off);
      v02p += __shfl_xor(v02p, off);
    }
    const float a2 = 2.f * v02p - 1.f;
    const float mn = sz2 - 2.f * z0p * z0p;
    const float cf = 1.f / sqrtf(fabsf(mn + 1e-7f));
    const float ab = cf * svz;
    const float b2 = cf * cf * sz2;
    const float den = 1.f + 2.f * ab + a2 * b2;
    const float inv = 0.25f / (den + 1e-7f);
    const float sx = (1.f + 2.f * ab + b2) * inv;
    const float sy = (1.f - a2) * cf * inv;
#pragma unroll
    for (int it = 0; it < 8; it++)
#pragma unroll
      for (int c = 0; c < 4; c++)
        macc[it][c] = fmaf(sx, vreg[it][c], fmaf(sy, zreg[it][c], macc[it][c]));
    if (lead) macc256 = fmaf(sx, v256, fmaf(sy, z256, macc256));
    __syncthreads();
  }

  float sm2 = 0.f, m02p = 0.f;
#pragma unroll
  for (int it = 0; it < 8; it++)
#pragma unroll
    for (int c = 0; c < 4; c++) sm2 = fmaf(macc[it][c], macc[it][c], sm2);
  if (lead) {
    sm2 = fmaf(macc256, macc256, sm2);
    m02p = macc[0][0] * macc[0][0];
  }
#pragma unroll
  for (int off = 1; off < 8; off <<= 1) {
    sm2 += __shfl_xor(sm2, off);
    m02p += __shfl_xor(m02p, off);
  }
  const float fv = 1.f / sqrtf(fabsf(sm2 - 2.f * m02p) + 1e-7f);
  float* orow = o + (long)(n0 + erow) * DIN;
#pragma unroll
  for (int it = 0; it < 8; it++)
#pragma unroll
    for (int c = 0; c < 4; c++) orow[it * 32 + ecol + c] = macc[it][c] * fv;
  if (lead) orow[256] = macc256 * fv;
}

extern "C" void kernel_launch(void* const* d_in, const int* in_sizes, int n_in,
                              void* d_out, int out_size, void* d_ws, size_t ws_size,
                              hipStream_t stream) {
  const float* u    = (const float*)d_in[0];
  const float* ii   = (const float*)d_in[1];
  const float* Wk   = (const float*)d_in[2];
  const float* bk   = (const float*)d_in[3];
  const float* Wq   = (const float*)d_in[4];
  const float* bq   = (const float*)d_in[5];
  const float* Wv   = (const float*)d_in[6];
  const float* bv   = (const float*)d_in[7];
  const float* proj = (const float*)d_in[8];
  float* out = (float*)d_out;

  const long NV = (long)HH * NR * DIN;
  const long NF = (long)HH * NR * MF;
  const long NLT = (long)HH * LTP * MF;
  float* v_u = (float*)d_ws;
  float* v_i = v_u + NV;
  bf16* qp_u = (bf16*)(v_i + NV);
  bf16* kp_u = qp_u + NF;
  bf16* qp_i = kp_u + NF;
  bf16* kp_i = qp_i + NF;
  bf16* ltHi_u = kp_i + NF;
  bf16* ltLo_u = ltHi_u + NLT;
  bf16* ltHi_i = ltLo_u + NLT;
  bf16* ltLo_i = ltHi_i + NLT;
  bf16* xb_u  = ltLo_i + NLT;
  bf16* xb_i  = xb_u + (long)NR * KP;
  bf16* WbTq  = xb_i + (long)NR * KP;
  bf16* WbTk  = WbTq + 4 * 256 * KP;
  bf16* WbTv  = WbTk + 4 * 256 * KP;
  bf16* projT = WbTv + 4 * 256 * KP;
  float* part = (float*)xb_u;  // 16.4 MB, aliases xb region (dead after proj)

  cvt_x_kernel<<<NR, KP, 0, stream>>>(u, xb_u);
  cvt_x_kernel<<<NR, KP, 0, stream>>>(ii, xb_i);
  cvt_w_kernel<<<dim3(1024, 3), KP, 0, stream>>>(Wq, Wk, Wv, WbTq, WbTk, WbTv);
  cvt_p_kernel<<<64, 256, 0, stream>>>(proj, projT);

  dim3 gv((NR + 127) / 128, HH, 2);  // 157 x 4 x 2
  value2_kernel<<<gv, 256, 0, stream>>>(xb_u, xb_i, WbTv, bv, v_u, v_i);
  dim3 gq((NR + 127) / 128, HH, 4);  // 157 x 4 x 4
  qk2_kernel<<<gq, 256, 0, stream>>>(xb_u, xb_i, WbTq, WbTk, bq, bk, projT,
                                     qp_u, kp_u, qp_i, kp_i);

  // side 0 (-> lastT_u) uses (v_i, kp_i); side 1 (-> lastT_i) uses (v_u, kp_u)
  last3_kernel<<<dim3(5, LKC, 8), 256, 0, stream>>>(v_i, kp_i, v_u, kp_u, part);
  reduce_last4<<<dim3(LTP, 8), 64, 0, stream>>>(part, ltHi_u, ltLo_u, ltHi_i, ltLo_i);

  fuse3_kernel<<<dim3(NR / 32, 2), 256, 0, stream>>>(
      qp_u, v_u, ltHi_u, ltLo_u, qp_i, v_i, ltHi_i, ltLo_i, out);
}

// Round 6
// 635.595 us; speedup vs baseline: 1.8149x; 1.0284x over previous
//
#include <hip/hip_runtime.h>
#include <hip/hip_bf16.h>

#define HH 4
#define NR 20000
#define DIN 257
#define DS 256
#define MF 64
#define KP 288   // padded K for bf16 staging (9 chunks of 32); k=257 is the bias-1 slot
#define LTP 272  // lastT padded d-rows
#define ZST 276  // fuse3 LDS z-tile row stride
#define LKC 25   // last3 split-K: 25 grid x 25 chunks x 32 rows = 20000

typedef __bf16 bf16;
typedef bf16 bf16x8 __attribute__((ext_vector_type(8)));
typedef bf16 bf16x4 __attribute__((ext_vector_type(4)));
typedef bf16 bf16x2 __attribute__((ext_vector_type(2)));
typedef float f32x4 __attribute__((ext_vector_type(4)));
typedef unsigned int u32x4 __attribute__((ext_vector_type(4)));

__device__ __forceinline__ void load_lds16(const void* g, void* l) {
  __builtin_amdgcn_global_load_lds((const __attribute__((address_space(1))) void*)g,
                                   (__attribute__((address_space(3))) void*)l,
                                   16, 0, 0);
}

// ---------------------------------------------------------------------------
// conversions
// ---------------------------------------------------------------------------
__global__ void cvt_x_kernel(const float* __restrict__ x, bf16* __restrict__ xb) {
  const int n = blockIdx.x, k = threadIdx.x;  // 288 threads
  bf16 v = (bf16)0.f;
  if (k < DIN) v = (bf16)x[(long)n * DIN + k];
  else if (k == DIN) v = (bf16)1.f;  // bias-1 slot (WbT pads are 0 there)
  xb[(long)n * KP + k] = v;
}

__global__ void cvt_w_kernel(const float* __restrict__ Wq, const float* __restrict__ Wk,
                             const float* __restrict__ Wv, bf16* __restrict__ WbTq,
                             bf16* __restrict__ WbTk, bf16* __restrict__ WbTv) {
  const int which = blockIdx.y;
  const int h = blockIdx.x >> 8, n = blockIdx.x & 255, k = threadIdx.x;
  const float* W = which == 0 ? Wq : (which == 1 ? Wk : Wv);
  bf16* o = which == 0 ? WbTq : (which == 1 ? WbTk : WbTv);
  o[((long)h * 256 + n) * KP + k] =
      (k < DIN) ? (bf16)W[((long)h * DIN + k) * DS + n] : (bf16)0.f;
}

// WpT[(which*HH+h)][m][k] = sum_d W[h][k][d]*proj[d][m]; k=257 row = b.proj
__global__ void cvt_wp_kernel(const float* __restrict__ Wq, const float* __restrict__ Wk,
                              const float* __restrict__ bq, const float* __restrict__ bk,
                              const float* __restrict__ proj, bf16* __restrict__ WpT) {
  const int k = blockIdx.x, h = blockIdx.y, which = blockIdx.z, m = threadIdx.x;
  const float* W = which ? Wk : Wq;
  const float* bb = which ? bk : bq;
  float acc = 0.f;
  if (k < DIN) {
    const float* wr = W + ((long)h * DIN + k) * DS;
#pragma unroll 8
    for (int d = 0; d < DS; d++) acc = fmaf(wr[d], proj[(long)d * MF + m], acc);
  } else if (k == DIN) {
    const float* br = bb + (long)h * DS;
#pragma unroll 8
    for (int d = 0; d < DS; d++) acc = fmaf(br[d], proj[(long)d * MF + m], acc);
  }
  WpT[(((long)which * HH + h) * MF + m) * KP + k] = (bf16)acc;
}

// ---------------------------------------------------------------------------
// proj3: all 6 projection GEMMs. grid (157, 4, 6).
// z: 0=value-u 1=value-i 2=q-u 3=k-u 4=q-i 5=k-i
// 128 rows x 256 cols, K chunks of 32. A and B both staged via
// global_load_lds width-16 in fragment-contiguous layouts.
// value mode: write hyperboloid (t, space) fp32. qk mode: write front factor.
// ---------------------------------------------------------------------------
__global__ __launch_bounds__(256) void proj3_kernel(
    const bf16* __restrict__ xbA, const bf16* __restrict__ xbB,
    const bf16* __restrict__ WbTq, const bf16* __restrict__ WbTk,
    const bf16* __restrict__ WbTv,
    const float* __restrict__ bq, const float* __restrict__ bk,
    const float* __restrict__ bv,
    float* __restrict__ voA, float* __restrict__ voB, float* __restrict__ fr)
{
  __shared__ __align__(16) unsigned char smem[26624];
  bf16* As = (bf16*)smem;              // [4 kq][128 row][8]  = 8192 B
  bf16* Bs = (bf16*)(smem + 8192);     // [4 kq][256 n][8]    = 16384 B
  float* rs = (float*)(smem + 24576);  // [128][4]            = 2048 B

  const int t = threadIdx.x;
  const int h = blockIdx.y;
  const int z = blockIdx.z;
  const int n0 = blockIdx.x * 128;
  const bf16* xb = (z == 1 || z >= 4) ? xbB : xbA;
  const bf16* WbT = (z < 2) ? WbTv : ((z == 2 || z == 4) ? WbTq : WbTk);
  const float* bsel = (z < 2) ? bv : ((z == 2 || z == 4) ? bq : bk);
  const int w = t >> 6, lane = t & 63;
  const int m16 = lane & 15, q = lane >> 4;

  f32x4 acc[8][4] = {};
  const bf16* wbh = WbT + (long)h * 256 * KP;

  for (int c = 0; c < 9; c++) {
    const int k0 = c * 32;
    // A stage: wave w = k-quad w; lane -> row s*64+lane; dest [w][row][8]
#pragma unroll
    for (int s = 0; s < 2; s++)
      load_lds16(xb + (long)min(n0 + s * 64 + lane, NR - 1) * KP + k0 + w * 8,
                 As + (w * 128 + s * 64) * 8);
    // B stage: wave w = k-quad w; lane -> col s*64+lane; dest [w][n][8]
#pragma unroll
    for (int s = 0; s < 4; s++)
      load_lds16(wbh + (long)(s * 64 + lane) * KP + k0 + w * 8,
                 Bs + (w * 256 + s * 64) * 8);
    __syncthreads();
    bf16x8 af[8], bfj[4];
#pragma unroll
    for (int i = 0; i < 8; i++)
      af[i] = *(const bf16x8*)(As + (q * 128 + i * 16 + m16) * 8);
#pragma unroll
    for (int j = 0; j < 4; j++)
      bfj[j] = *(const bf16x8*)(Bs + (q * 256 + w * 64 + j * 16 + m16) * 8);
#pragma unroll
    for (int i = 0; i < 8; i++)
#pragma unroll
      for (int j = 0; j < 4; j++)
        acc[i][j] = __builtin_amdgcn_mfma_f32_16x16x32_bf16(af[i], bfj[j], acc[i][j], 0, 0, 0);
    __syncthreads();
  }

  float bias[4];
#pragma unroll
  for (int j = 0; j < 4; j++) bias[j] = bsel[h * DS + w * 64 + j * 16 + m16];
#pragma unroll
  for (int i = 0; i < 8; i++)
#pragma unroll
    for (int r = 0; r < 4; r++) {
      float s = 0.f;
#pragma unroll
      for (int j = 0; j < 4; j++) {
        acc[i][j][r] += bias[j];
        s = fmaf(acc[i][j][r], acc[i][j][r], s);
      }
      for (int off = 1; off < 16; off <<= 1) s += __shfl_xor(s, off);
      if (m16 == 0) rs[(i * 16 + q * 4 + r) * 4 + w] = s;
    }
  __syncthreads();

  if (z < 2) {
    float* vout = z ? voB : voA;
    if (t < 128) {
      const float ss = rs[t * 4] + rs[t * 4 + 1] + rs[t * 4 + 2] + rs[t * 4 + 3];
      if (n0 + t < NR) vout[((long)h * NR + n0 + t) * DIN] = sqrtf(1.f + ss);
    }
#pragma unroll
    for (int i = 0; i < 8; i++) {
      const int row = i * 16 + q * 4;
#pragma unroll
      for (int r = 0; r < 4; r++) {
        const int rg = n0 + row + r;
        if (rg < NR) {
          float* vo = vout + ((long)h * NR + rg) * DIN + 1 + w * 64 + m16;
          vo[0] = acc[i][0][r]; vo[16] = acc[i][1][r];
          vo[32] = acc[i][2][r]; vo[48] = acc[i][3][r];
        }
      }
    }
  } else {
    if (t < 128 && n0 + t < NR) {
      const float ss = rs[t * 4] + rs[t * 4 + 1] + rs[t * 4 + 2] + rs[t * 4 + 3];
      fr[((long)(z - 2) * HH + h) * NR + n0 + t] = 0.125f * __expf(-ss) + 1e-8f;
    }
  }
}

// ---------------------------------------------------------------------------
// feat: features = exp(sqrt(2) * (x @ WpT^T)) * front. Zero LDS; A/B frags
// straight from global. grid (157, 4, 4); combo c: 0=q-u 1=k-u 2=q-i 3=k-i.
// ---------------------------------------------------------------------------
__global__ __launch_bounds__(256) void feat_kernel(
    const bf16* __restrict__ xbA, const bf16* __restrict__ xbB,
    const bf16* __restrict__ WpT, const float* __restrict__ fr,
    bf16* __restrict__ qpA, bf16* __restrict__ kpA,
    bf16* __restrict__ qpB, bf16* __restrict__ kpB)
{
  const int t = threadIdx.x;
  const int h = blockIdx.y;
  const int c = blockIdx.z;
  const int n0 = blockIdx.x * 128;
  const bf16* xb = (c >= 2) ? xbB : xbA;
  const bf16* wp = WpT + (((long)(c & 1) * HH + h) * MF) * KP;
  bf16* fout = (c == 0) ? qpA : (c == 1) ? kpA : (c == 2) ? qpB : kpB;
  const float* frc = fr + ((long)c * HH + h) * NR;
  const int w = t >> 6, lane = t & 63;
  const int m16 = lane & 15, q = lane >> 4;
  const int r0 = w * 32;  // wave's 32-row strip

  f32x4 acc[2][4] = {};
  for (int c9 = 0; c9 < 9; c9++) {
    const int k0 = c9 * 32 + q * 8;
    bf16x8 af[2], bfj[4];
#pragma unroll
    for (int i = 0; i < 2; i++)
      af[i] = *(const bf16x8*)(xb + (long)min(n0 + r0 + i * 16 + m16, NR - 1) * KP + k0);
#pragma unroll
    for (int j = 0; j < 4; j++)
      bfj[j] = *(const bf16x8*)(wp + (long)(j * 16 + m16) * KP + k0);
#pragma unroll
    for (int i = 0; i < 2; i++)
#pragma unroll
      for (int j = 0; j < 4; j++)
        acc[i][j] = __builtin_amdgcn_mfma_f32_16x16x32_bf16(af[i], bfj[j], acc[i][j], 0, 0, 0);
  }
  const float SQ2 = 1.41421356237309515f;  // 1/sqrt(tau)
#pragma unroll
  for (int i = 0; i < 2; i++)
#pragma unroll
    for (int r = 0; r < 4; r++) {
      const int rg = n0 + r0 + i * 16 + q * 4 + r;
      if (rg < NR) {
        const float frv = frc[rg];
        bf16* fo = fout + ((long)h * NR + rg) * MF + m16;
#pragma unroll
        for (int j = 0; j < 4; j++)
          fo[j * 16] = (bf16)(__expf(SQ2 * acc[i][j][r]) * frv);
      }
    }
}

// ---------------------------------------------------------------------------
// last3: MFMA lastT[d][m] = sum_n v[n][d]*f[n][m]. grid (5, 25, 8). (unchanged)
// ---------------------------------------------------------------------------
__global__ __launch_bounds__(256) void last3_kernel(
    const float* __restrict__ vA, const bf16* __restrict__ fA,
    const float* __restrict__ vB, const bf16* __restrict__ fB,
    float* __restrict__ part)
{
  __shared__ unsigned int Va[64 * 17];
  __shared__ unsigned int Fa[64 * 17];
  const int t = threadIdx.x;
  const int dt = blockIdx.x, kc = blockIdx.y, z = blockIdx.z;
  const int side = z >> 2, h = z & 3;
  const float* v = side ? vB : vA;
  const bf16* f = side ? fB : fA;
  const int d0 = dt * 64;
  const int w = t >> 6, lane = t & 63;
  const int m16 = lane & 15, q = lane >> 4;
  const int np = t >> 4, xg = (t & 15) * 4;
  f32x4 acc[4] = {};

  for (int c = 0; c < LKC; c++) {
    const int n0 = (kc * LKC + c) * 32;
    {
      const float* s0 = v + ((long)h * NR + n0 + 2 * np) * DIN + d0 + xg;
      const float* s1 = s0 + DIN;
      if (d0 + xg + 3 < DIN) {
        const f32x4 a0 = *(const f32x4*)s0;
        const f32x4 a1 = *(const f32x4*)s1;
#pragma unroll
        for (int e = 0; e < 4; e++) {
          bf16x2 p; p[0] = (bf16)a0[e]; p[1] = (bf16)a1[e];
          Va[(xg + e) * 17 + np] = __builtin_bit_cast(unsigned int, p);
        }
      } else {
#pragma unroll
        for (int e = 0; e < 4; e++) {
          float a0 = 0.f, a1 = 0.f;
          if (d0 + xg + e < DIN) { a0 = s0[e]; a1 = s1[e]; }
          bf16x2 p; p[0] = (bf16)a0; p[1] = (bf16)a1;
          Va[(xg + e) * 17 + np] = __builtin_bit_cast(unsigned int, p);
        }
      }
    }
    {
      const bf16* s0 = f + ((long)h * NR + n0 + 2 * np) * MF + xg;
      const bf16x4 f0 = *(const bf16x4*)s0;
      const bf16x4 f1 = *(const bf16x4*)(s0 + MF);
#pragma unroll
      for (int e = 0; e < 4; e++) {
        bf16x2 p; p[0] = f0[e]; p[1] = f1[e];
        Fa[(xg + e) * 17 + np] = __builtin_bit_cast(unsigned int, p);
      }
    }
    __syncthreads();
    u32x4 bw;
#pragma unroll
    for (int c4 = 0; c4 < 4; c4++) bw[c4] = Fa[(w * 16 + m16) * 17 + q * 4 + c4];
    const bf16x8 bv = __builtin_bit_cast(bf16x8, bw);
#pragma unroll
    for (int i = 0; i < 4; i++) {
      u32x4 aw;
#pragma unroll
      for (int c4 = 0; c4 < 4; c4++) aw[c4] = Va[(i * 16 + m16) * 17 + q * 4 + c4];
      acc[i] = __builtin_amdgcn_mfma_f32_16x16x32_bf16(
          __builtin_bit_cast(bf16x8, aw), bv, acc[i], 0, 0, 0);
    }
    __syncthreads();
  }
  float* pp = part + ((long)(z * LKC + kc) * 5 + dt) * 4096;
#pragma unroll
  for (int i = 0; i < 4; i++)
#pragma unroll
    for (int r = 0; r < 4; r++)
      pp[(i * 16 + q * 4 + r) * 64 + w * 16 + m16] = acc[i][r];
}

__global__ void reduce_last4(const float* __restrict__ part,
                             bf16* __restrict__ hiU, bf16* __restrict__ loU,
                             bf16* __restrict__ hiI, bf16* __restrict__ loI) {
  const int d = blockIdx.x, zz = blockIdx.y, m = threadIdx.x;  // (272, 8) x 64
  const int side = zz >> 2, h = zz & 3;
  const int dt = d >> 6, dl = d & 63;
  float s = 0.f;
#pragma unroll 5
  for (int kc = 0; kc < LKC; kc++)
    s += part[((long)(zz * LKC + kc) * 5 + dt) * 4096 + dl * 64 + m];
  bf16* hi = side ? hiI : hiU;
  bf16* lo = side ? loI : loU;
  const bf16 hv = (bf16)s;
  hi[((long)h * LTP + d) * MF + m] = hv;
  lo[((long)h * LTP + d) * MF + m] = (bf16)(s - (float)hv);
}

// ---------------------------------------------------------------------------
// fuse3 (unchanged)
// ---------------------------------------------------------------------------
__global__ __launch_bounds__(256) void fuse3_kernel(
    const bf16* __restrict__ qpA, const float* __restrict__ vA,
    const bf16* __restrict__ hiA, const bf16* __restrict__ loA,
    const bf16* __restrict__ qpB, const float* __restrict__ vB,
    const bf16* __restrict__ hiB, const bf16* __restrict__ loB,
    float* __restrict__ out)
{
  __shared__ __align__(16) float zs[32 * ZST];

  const int side = blockIdx.y;
  const bf16* qp = side ? qpB : qpA;
  const float* v = side ? vB : vA;
  const bf16* hi = side ? hiB : hiA;
  const bf16* lo = side ? loB : loA;
  float* o = out + (long)side * NR * DIN;

  const int t = threadIdx.x;
  const int n0 = blockIdx.x * 32;
  const int w = t >> 6, lane = t & 63;
  const int m16 = lane & 15, q = lane >> 4;
  const int erow = t >> 3, ecol = (t & 7) * 4;
  const bool lead = ((t & 7) == 0);
  const int ntile = (w == 0) ? 5 : 4;

  f32x4 macc[8] = {};
  float macc256 = 0.f;

  for (int h = 0; h < HH; h++) {
    const float* vr = v + ((long)h * NR + n0 + erow) * DIN;
    f32x4 vreg[8];
#pragma unroll
    for (int it = 0; it < 8; it++)
      vreg[it] = *(const f32x4*)(vr + it * 32 + ecol);
    float v256 = lead ? vr[256] : 0.f;

    bf16x8 af[2][2];
#pragma unroll
    for (int i = 0; i < 2; i++)
#pragma unroll
      for (int hf = 0; hf < 2; hf++)
        af[i][hf] = *(const bf16x8*)(qp + ((long)h * NR + n0 + i * 16 + m16) * MF + hf * 32 + q * 8);

    for (int jt = 0; jt < ntile; jt++) {
      const int dt = (jt < 4) ? (w + jt * 4) : 16;
      const int d = dt * 16 + m16;
      const bf16* ph = hi + ((long)h * LTP + d) * MF + q * 8;
      const bf16* pl = lo + ((long)h * LTP + d) * MF + q * 8;
      const bf16x8 bh0 = *(const bf16x8*)ph, bh1 = *(const bf16x8*)(ph + 32);
      const bf16x8 bl0 = *(const bf16x8*)pl, bl1 = *(const bf16x8*)(pl + 32);
#pragma unroll
      for (int i = 0; i < 2; i++) {
        f32x4 a = {0.f, 0.f, 0.f, 0.f};
        a = __builtin_amdgcn_mfma_f32_16x16x32_bf16(af[i][1], bl1, a, 0, 0, 0);
        a = __builtin_amdgcn_mfma_f32_16x16x32_bf16(af[i][0], bl0, a, 0, 0, 0);
        a = __builtin_amdgcn_mfma_f32_16x16x32_bf16(af[i][1], bh1, a, 0, 0, 0);
        a = __builtin_amdgcn_mfma_f32_16x16x32_bf16(af[i][0], bh0, a, 0, 0, 0);
#pragma unroll
        for (int r = 0; r < 4; r++)
          zs[(i * 16 + q * 4 + r) * ZST + d] = a[r];
      }
    }
    __syncthreads();

    f32x4 zreg[8];
    float sz2 = 0.f, svz = 0.f, z0p = 0.f, v02p = 0.f;
#pragma unroll
    for (int it = 0; it < 8; it++) {
      zreg[it] = *(const f32x4*)&zs[erow * ZST + it * 32 + ecol];
#pragma unroll
      for (int c = 0; c < 4; c++) {
        sz2 = fmaf(zreg[it][c], zreg[it][c], sz2);
        svz = fmaf(vreg[it][c], zreg[it][c], svz);
      }
    }
    float z256 = 0.f;
    if (lead) {
      z256 = zs[erow * ZST + 256];
      sz2 = fmaf(z256, z256, sz2);
      svz = fmaf(v256, z256, svz);
      z0p = zreg[0][0];
      v02p = vreg[0][0] * vreg[0][0];
    }
#pragma unroll
    for (int off = 1; off < 8; off <<= 1) {
      sz2 += __shfl_xor(sz2, off);
      svz += __shfl_xor(svz, off);
      z0p += __shfl_xor(z0p, off);
      v02p += __shfl_xor(v02p, off);
    }
    const float a2 = 2.f * v02p - 1.f;
    const float mn = sz2 - 2.f * z0p * z0p;
    const float cf = 1.f / sqrtf(fabsf(mn + 1e-7f));
    const float ab = cf * svz;
    const float b2 = cf * cf * sz2;
    const float den = 1.f + 2.f * ab + a2 * b2;
    const float inv = 0.25f / (den + 1e-7f);
    const float sx = (1.f + 2.f * ab + b2) * inv;
    const float sy = (1.f - a2) * cf * inv;
#pragma unroll
    for (int it = 0; it < 8; it++)
#pragma unroll
      for (int c = 0; c < 4; c++)
        macc[it][c] = fmaf(sx, vreg[it][c], fmaf(sy, zreg[it][c], macc[it][c]));
    if (lead) macc256 = fmaf(sx, v256, fmaf(sy, z256, macc256));
    __syncthreads();
  }

  float sm2 = 0.f, m02p = 0.f;
#pragma unroll
  for (int it = 0; it < 8; it++)
#pragma unroll
    for (int c = 0; c < 4; c++) sm2 = fmaf(macc[it][c], macc[it][c], sm2);
  if (lead) {
    sm2 = fmaf(macc256, macc256, sm2);
    m02p = macc[0][0] * macc[0][0];
  }
#pragma unroll
  for (int off = 1; off < 8; off <<= 1) {
    sm2 += __shfl_xor(sm2, off);
    m02p += __shfl_xor(m02p, off);
  }
  const float fv = 1.f / sqrtf(fabsf(sm2 - 2.f * m02p) + 1e-7f);
  float* orow = o + (long)(n0 + erow) * DIN;
#pragma unroll
  for (int it = 0; it < 8; it++)
#pragma unroll
    for (int c = 0; c < 4; c++) orow[it * 32 + ecol + c] = macc[it][c] * fv;
  if (lead) orow[256] = macc256 * fv;
}

extern "C" void kernel_launch(void* const* d_in, const int* in_sizes, int n_in,
                              void* d_out, int out_size, void* d_ws, size_t ws_size,
                              hipStream_t stream) {
  const float* u    = (const float*)d_in[0];
  const float* ii   = (const float*)d_in[1];
  const float* Wk   = (const float*)d_in[2];
  const float* bk   = (const float*)d_in[3];
  const float* Wq   = (const float*)d_in[4];
  const float* bq   = (const float*)d_in[5];
  const float* Wv   = (const float*)d_in[6];
  const float* bv   = (const float*)d_in[7];
  const float* proj = (const float*)d_in[8];
  float* out = (float*)d_out;

  const long NV = (long)HH * NR * DIN;
  const long NF = (long)HH * NR * MF;
  const long NLT = (long)HH * LTP * MF;
  float* v_u = (float*)d_ws;
  float* v_i = v_u + NV;
  bf16* qp_u = (bf16*)(v_i + NV);
  bf16* kp_u = qp_u + NF;
  bf16* qp_i = kp_u + NF;
  bf16* kp_i = qp_i + NF;
  bf16* ltHi_u = kp_i + NF;
  bf16* ltLo_u = ltHi_u + NLT;
  bf16* ltHi_i = ltLo_u + NLT;
  bf16* ltLo_i = ltHi_i + NLT;
  bf16* xb_u  = ltLo_i + NLT;
  bf16* xb_i  = xb_u + (long)NR * KP;
  bf16* WbTq  = xb_i + (long)NR * KP;
  bf16* WbTk  = WbTq + 4 * 256 * KP;
  bf16* WbTv  = WbTk + 4 * 256 * KP;
  bf16* WpT   = WbTv + 4 * 256 * KP;   // 8 * 64 * KP bf16
  float* fr   = (float*)(WpT + 8 * 64 * KP);  // 16 * NR fp32
  float* part = (float*)xb_u;  // 16.4 MB split-K partials, alias xb (dead after feat)

  cvt_x_kernel<<<NR, KP, 0, stream>>>(u, xb_u);
  cvt_x_kernel<<<NR, KP, 0, stream>>>(ii, xb_i);
  cvt_w_kernel<<<dim3(1024, 3), KP, 0, stream>>>(Wq, Wk, Wv, WbTq, WbTk, WbTv);
  cvt_wp_kernel<<<dim3(KP, HH, 2), 64, 0, stream>>>(Wq, Wk, bq, bk, proj, WpT);

  proj3_kernel<<<dim3((NR + 127) / 128, HH, 6), 256, 0, stream>>>(
      xb_u, xb_i, WbTq, WbTk, WbTv, bq, bk, bv, v_u, v_i, fr);
  feat_kernel<<<dim3((NR + 127) / 128, HH, 4), 256, 0, stream>>>(
      xb_u, xb_i, WpT, fr, qp_u, kp_u, qp_i, kp_i);

  // side 0 (-> lastT_u) uses (v_i, kp_i); side 1 (-> lastT_i) uses (v_u, kp_u)
  last3_kernel<<<dim3(5, LKC, 8), 256, 0, stream>>>(v_i, kp_i, v_u, kp_u, part);
  reduce_last4<<<dim3(LTP, 8), 64, 0, stream>>>(part, ltHi_u, ltLo_u, ltHi_i, ltLo_i);

  fuse3_kernel<<<dim3(NR / 32, 2), 256, 0, stream>>>(
      qp_u, v_u, ltHi_u, ltLo_u, qp_i, v_i, ltHi_i, ltLo_i, out);
}

// Round 7
// 587.824 us; speedup vs baseline: 1.9623x; 1.0813x over previous
//
#include <hip/hip_runtime.h>
#include <hip/hip_bf16.h>

#define HH 4
#define NR 20000
#define DIN 257
#define DS 256
#define MF 64
#define KP 288   // padded K for bf16 staging; k=257 is the bias-1 slot
#define LTP 272  // lastT padded d-rows
#define ZST 276  // fuse3 LDS z-tile row stride
#define LKC 25   // last3 split-K: 25 grid x 25 chunks x 32 rows = 20000

typedef __bf16 bf16;
typedef bf16 bf16x8 __attribute__((ext_vector_type(8)));
typedef bf16 bf16x4 __attribute__((ext_vector_type(4)));
typedef bf16 bf16x2 __attribute__((ext_vector_type(2)));
typedef float f32x4 __attribute__((ext_vector_type(4)));
typedef unsigned int u32x4 __attribute__((ext_vector_type(4)));

// ---------------------------------------------------------------------------
// conversions
// ---------------------------------------------------------------------------
__global__ void cvt_x_kernel(const float* __restrict__ x, bf16* __restrict__ xb) {
  const int n = blockIdx.x, k = threadIdx.x;  // 288 threads
  bf16 v = (bf16)0.f;
  if (k < DIN) v = (bf16)x[(long)n * DIN + k];
  else if (k == DIN) v = (bf16)1.f;  // bias-1 slot (WbT pads are 0 there)
  xb[(long)n * KP + k] = v;
}

__global__ void cvt_w_kernel(const float* __restrict__ Wq, const float* __restrict__ Wk,
                             const float* __restrict__ Wv, bf16* __restrict__ WbTq,
                             bf16* __restrict__ WbTk, bf16* __restrict__ WbTv) {
  const int which = blockIdx.y;
  const int h = blockIdx.x >> 8, n = blockIdx.x & 255, k = threadIdx.x;
  const float* W = which == 0 ? Wq : (which == 1 ? Wk : Wv);
  bf16* o = which == 0 ? WbTq : (which == 1 ? WbTk : WbTv);
  o[((long)h * 256 + n) * KP + k] =
      (k < DIN) ? (bf16)W[((long)h * DIN + k) * DS + n] : (bf16)0.f;
}

// WpT[(which*HH+h)][m][k] = sum_d W[h][k][d]*proj[d][m]; k=257 row = b.proj
__global__ void cvt_wp_kernel(const float* __restrict__ Wq, const float* __restrict__ Wk,
                              const float* __restrict__ bq, const float* __restrict__ bk,
                              const float* __restrict__ proj, bf16* __restrict__ WpT) {
  const int k = blockIdx.x, h = blockIdx.y, which = blockIdx.z, m = threadIdx.x;
  const float* W = which ? Wk : Wq;
  const float* bb = which ? bk : bq;
  float acc = 0.f;
  if (k < DIN) {
    const float* wr = W + ((long)h * DIN + k) * DS;
#pragma unroll 8
    for (int d = 0; d < DS; d++) acc = fmaf(wr[d], proj[(long)d * MF + m], acc);
  } else if (k == DIN) {
    const float* br = bb + (long)h * DS;
#pragma unroll 8
    for (int d = 0; d < DS; d++) acc = fmaf(br[d], proj[(long)d * MF + m], acc);
  }
  WpT[(((long)which * HH + h) * MF + m) * KP + k] = (bf16)acc;
}

// ---------------------------------------------------------------------------
// proj4: barrier-free zero-LDS projection GEMM. grid (313, 4, 6).
// z: 0=value-u 1=value-i 2=q-u 3=k-u 4=q-i 5=k-i
// Block = 64 rows x 256 cols; wave w owns cols w*64..w*64+63 (acc 4x4).
// A-frags and B-frags loaded directly from global (A coalesced 16x64B,
// B is 147 KB/head -> L2-resident). 1-deep software pipeline over 9 K-chunks,
// NO __syncthreads in the K-loop.
// ---------------------------------------------------------------------------
__global__ __launch_bounds__(256) void proj4_kernel(
    const bf16* __restrict__ xbA, const bf16* __restrict__ xbB,
    const bf16* __restrict__ WbTq, const bf16* __restrict__ WbTk,
    const bf16* __restrict__ WbTv,
    const float* __restrict__ bq, const float* __restrict__ bk,
    const float* __restrict__ bv,
    float* __restrict__ voA, float* __restrict__ voB, float* __restrict__ fr)
{
  __shared__ float rs[64][4];

  const int t = threadIdx.x;
  const int h = blockIdx.y;
  const int z = blockIdx.z;
  const int n0 = blockIdx.x * 64;
  const bf16* xb = (z == 1 || z >= 4) ? xbB : xbA;
  const bf16* WbT = (z < 2) ? WbTv : ((z == 2 || z == 4) ? WbTq : WbTk);
  const float* bsel = (z < 2) ? bv : ((z == 2 || z == 4) ? bq : bk);
  const int w = t >> 6, lane = t & 63;
  const int m16 = lane & 15, q = lane >> 4;

  // per-lane base pointers
  const bf16* aptr[4];
#pragma unroll
  for (int i = 0; i < 4; i++)
    aptr[i] = xb + (long)min(n0 + i * 16 + m16, NR - 1) * KP + q * 8;
  const bf16* bptr[4];
  const bf16* wbh = WbT + (long)h * 256 * KP;
#pragma unroll
  for (int j = 0; j < 4; j++)
    bptr[j] = wbh + (long)(w * 64 + j * 16 + m16) * KP + q * 8;

  f32x4 acc[4][4] = {};
  bf16x8 afc[4], bfc[4], afn[4], bfn[4];
#pragma unroll
  for (int i = 0; i < 4; i++) afc[i] = *(const bf16x8*)(aptr[i]);
#pragma unroll
  for (int j = 0; j < 4; j++) bfc[j] = *(const bf16x8*)(bptr[j]);

  for (int c = 0; c < 9; c++) {
    if (c < 8) {
      const int k1 = (c + 1) * 32;
#pragma unroll
      for (int i = 0; i < 4; i++) afn[i] = *(const bf16x8*)(aptr[i] + k1);
#pragma unroll
      for (int j = 0; j < 4; j++) bfn[j] = *(const bf16x8*)(bptr[j] + k1);
    }
#pragma unroll
    for (int i = 0; i < 4; i++)
#pragma unroll
      for (int j = 0; j < 4; j++)
        acc[i][j] = __builtin_amdgcn_mfma_f32_16x16x32_bf16(afc[i], bfc[j], acc[i][j], 0, 0, 0);
#pragma unroll
    for (int i = 0; i < 4; i++) afc[i] = afn[i];
#pragma unroll
    for (int j = 0; j < 4; j++) bfc[j] = bfn[j];
  }

  float bias[4];
#pragma unroll
  for (int j = 0; j < 4; j++) bias[j] = bsel[h * DS + w * 64 + j * 16 + m16];
#pragma unroll
  for (int i = 0; i < 4; i++)
#pragma unroll
    for (int r = 0; r < 4; r++) {
      float s = 0.f;
#pragma unroll
      for (int j = 0; j < 4; j++) {
        acc[i][j][r] += bias[j];
        s = fmaf(acc[i][j][r], acc[i][j][r], s);
      }
      for (int off = 1; off < 16; off <<= 1) s += __shfl_xor(s, off);
      if (m16 == 0) rs[i * 16 + q * 4 + r][w] = s;
    }
  __syncthreads();

  if (z < 2) {
    float* vout = z ? voB : voA;
    if (t < 64) {
      const float ss = rs[t][0] + rs[t][1] + rs[t][2] + rs[t][3];
      if (n0 + t < NR) vout[((long)h * NR + n0 + t) * DIN] = sqrtf(1.f + ss);
    }
#pragma unroll
    for (int i = 0; i < 4; i++) {
      const int row = i * 16 + q * 4;
#pragma unroll
      for (int r = 0; r < 4; r++) {
        const int rg = n0 + row + r;
        if (rg < NR) {
          float* vo = vout + ((long)h * NR + rg) * DIN + 1 + w * 64 + m16;
          vo[0] = acc[i][0][r]; vo[16] = acc[i][1][r];
          vo[32] = acc[i][2][r]; vo[48] = acc[i][3][r];
        }
      }
    }
  } else {
    if (t < 64 && n0 + t < NR) {
      const float ss = rs[t][0] + rs[t][1] + rs[t][2] + rs[t][3];
      fr[((long)(z - 2) * HH + h) * NR + n0 + t] = 0.125f * __expf(-ss) + 1e-8f;
    }
  }
}

// ---------------------------------------------------------------------------
// feat: features = exp(sqrt(2) * (x @ WpT^T)) * front. Zero LDS. (unchanged)
// ---------------------------------------------------------------------------
__global__ __launch_bounds__(256) void feat_kernel(
    const bf16* __restrict__ xbA, const bf16* __restrict__ xbB,
    const bf16* __restrict__ WpT, const float* __restrict__ fr,
    bf16* __restrict__ qpA, bf16* __restrict__ kpA,
    bf16* __restrict__ qpB, bf16* __restrict__ kpB)
{
  const int t = threadIdx.x;
  const int h = blockIdx.y;
  const int c = blockIdx.z;
  const int n0 = blockIdx.x * 128;
  const bf16* xb = (c >= 2) ? xbB : xbA;
  const bf16* wp = WpT + (((long)(c & 1) * HH + h) * MF) * KP;
  bf16* fout = (c == 0) ? qpA : (c == 1) ? kpA : (c == 2) ? qpB : kpB;
  const float* frc = fr + ((long)c * HH + h) * NR;
  const int w = t >> 6, lane = t & 63;
  const int m16 = lane & 15, q = lane >> 4;
  const int r0 = w * 32;

  f32x4 acc[2][4] = {};
  for (int c9 = 0; c9 < 9; c9++) {
    const int k0 = c9 * 32 + q * 8;
    bf16x8 af[2], bfj[4];
#pragma unroll
    for (int i = 0; i < 2; i++)
      af[i] = *(const bf16x8*)(xb + (long)min(n0 + r0 + i * 16 + m16, NR - 1) * KP + k0);
#pragma unroll
    for (int j = 0; j < 4; j++)
      bfj[j] = *(const bf16x8*)(wp + (long)(j * 16 + m16) * KP + k0);
#pragma unroll
    for (int i = 0; i < 2; i++)
#pragma unroll
      for (int j = 0; j < 4; j++)
        acc[i][j] = __builtin_amdgcn_mfma_f32_16x16x32_bf16(af[i], bfj[j], acc[i][j], 0, 0, 0);
  }
  const float SQ2 = 1.41421356237309515f;
#pragma unroll
  for (int i = 0; i < 2; i++)
#pragma unroll
    for (int r = 0; r < 4; r++) {
      const int rg = n0 + r0 + i * 16 + q * 4 + r;
      if (rg < NR) {
        const float frv = frc[rg];
        bf16* fo = fout + ((long)h * NR + rg) * MF + m16;
#pragma unroll
        for (int j = 0; j < 4; j++)
          fo[j * 16] = (bf16)(__expf(SQ2 * acc[i][j][r]) * frv);
      }
    }
}

// ---------------------------------------------------------------------------
// last3: MFMA lastT[d][m] = sum_n v[n][d]*f[n][m]. grid (5, 25, 8). (unchanged)
// ---------------------------------------------------------------------------
__global__ __launch_bounds__(256) void last3_kernel(
    const float* __restrict__ vA, const bf16* __restrict__ fA,
    const float* __restrict__ vB, const bf16* __restrict__ fB,
    float* __restrict__ part)
{
  __shared__ unsigned int Va[64 * 17];
  __shared__ unsigned int Fa[64 * 17];
  const int t = threadIdx.x;
  const int dt = blockIdx.x, kc = blockIdx.y, z = blockIdx.z;
  const int side = z >> 2, h = z & 3;
  const float* v = side ? vB : vA;
  const bf16* f = side ? fB : fA;
  const int d0 = dt * 64;
  const int w = t >> 6, lane = t & 63;
  const int m16 = lane & 15, q = lane >> 4;
  const int np = t >> 4, xg = (t & 15) * 4;
  f32x4 acc[4] = {};

  for (int c = 0; c < LKC; c++) {
    const int n0 = (kc * LKC + c) * 32;
    {
      const float* s0 = v + ((long)h * NR + n0 + 2 * np) * DIN + d0 + xg;
      const float* s1 = s0 + DIN;
      if (d0 + xg + 3 < DIN) {
        const f32x4 a0 = *(const f32x4*)s0;
        const f32x4 a1 = *(const f32x4*)s1;
#pragma unroll
        for (int e = 0; e < 4; e++) {
          bf16x2 p; p[0] = (bf16)a0[e]; p[1] = (bf16)a1[e];
          Va[(xg + e) * 17 + np] = __builtin_bit_cast(unsigned int, p);
        }
      } else {
#pragma unroll
        for (int e = 0; e < 4; e++) {
          float a0 = 0.f, a1 = 0.f;
          if (d0 + xg + e < DIN) { a0 = s0[e]; a1 = s1[e]; }
          bf16x2 p; p[0] = (bf16)a0; p[1] = (bf16)a1;
          Va[(xg + e) * 17 + np] = __builtin_bit_cast(unsigned int, p);
        }
      }
    }
    {
      const bf16* s0 = f + ((long)h * NR + n0 + 2 * np) * MF + xg;
      const bf16x4 f0 = *(const bf16x4*)s0;
      const bf16x4 f1 = *(const bf16x4*)(s0 + MF);
#pragma unroll
      for (int e = 0; e < 4; e++) {
        bf16x2 p; p[0] = f0[e]; p[1] = f1[e];
        Fa[(xg + e) * 17 + np] = __builtin_bit_cast(unsigned int, p);
      }
    }
    __syncthreads();
    u32x4 bw;
#pragma unroll
    for (int c4 = 0; c4 < 4; c4++) bw[c4] = Fa[(w * 16 + m16) * 17 + q * 4 + c4];
    const bf16x8 bv = __builtin_bit_cast(bf16x8, bw);
#pragma unroll
    for (int i = 0; i < 4; i++) {
      u32x4 aw;
#pragma unroll
      for (int c4 = 0; c4 < 4; c4++) aw[c4] = Va[(i * 16 + m16) * 17 + q * 4 + c4];
      acc[i] = __builtin_amdgcn_mfma_f32_16x16x32_bf16(
          __builtin_bit_cast(bf16x8, aw), bv, acc[i], 0, 0, 0);
    }
    __syncthreads();
  }
  float* pp = part + ((long)(z * LKC + kc) * 5 + dt) * 4096;
#pragma unroll
  for (int i = 0; i < 4; i++)
#pragma unroll
    for (int r = 0; r < 4; r++)
      pp[(i * 16 + q * 4 + r) * 64 + w * 16 + m16] = acc[i][r];
}

__global__ void reduce_last4(const float* __restrict__ part,
                             bf16* __restrict__ hiU, bf16* __restrict__ loU,
                             bf16* __restrict__ hiI, bf16* __restrict__ loI) {
  const int d = blockIdx.x, zz = blockIdx.y, m = threadIdx.x;  // (272, 8) x 64
  const int side = zz >> 2, h = zz & 3;
  const int dt = d >> 6, dl = d & 63;
  float s = 0.f;
#pragma unroll 5
  for (int kc = 0; kc < LKC; kc++)
    s += part[((long)(zz * LKC + kc) * 5 + dt) * 4096 + dl * 64 + m];
  bf16* hi = side ? hiI : hiU;
  bf16* lo = side ? loI : loU;
  const bf16 hv = (bf16)s;
  hi[((long)h * LTP + d) * MF + m] = hv;
  lo[((long)h * LTP + d) * MF + m] = (bf16)(s - (float)hv);
}

// ---------------------------------------------------------------------------
// fuse3 (unchanged)
// ---------------------------------------------------------------------------
__global__ __launch_bounds__(256) void fuse3_kernel(
    const bf16* __restrict__ qpA, const float* __restrict__ vA,
    const bf16* __restrict__ hiA, const bf16* __restrict__ loA,
    const bf16* __restrict__ qpB, const float* __restrict__ vB,
    const bf16* __restrict__ hiB, const bf16* __restrict__ loB,
    float* __restrict__ out)
{
  __shared__ __align__(16) float zs[32 * ZST];

  const int side = blockIdx.y;
  const bf16* qp = side ? qpB : qpA;
  const float* v = side ? vB : vA;
  const bf16* hi = side ? hiB : hiA;
  const bf16* lo = side ? loB : loA;
  float* o = out + (long)side * NR * DIN;

  const int t = threadIdx.x;
  const int n0 = blockIdx.x * 32;
  const int w = t >> 6, lane = t & 63;
  const int m16 = lane & 15, q = lane >> 4;
  const int erow = t >> 3, ecol = (t & 7) * 4;
  const bool lead = ((t & 7) == 0);
  const int ntile = (w == 0) ? 5 : 4;

  f32x4 macc[8] = {};
  float macc256 = 0.f;

  for (int h = 0; h < HH; h++) {
    const float* vr = v + ((long)h * NR + n0 + erow) * DIN;
    f32x4 vreg[8];
#pragma unroll
    for (int it = 0; it < 8; it++)
      vreg[it] = *(const f32x4*)(vr + it * 32 + ecol);
    float v256 = lead ? vr[256] : 0.f;

    bf16x8 af[2][2];
#pragma unroll
    for (int i = 0; i < 2; i++)
#pragma unroll
      for (int hf = 0; hf < 2; hf++)
        af[i][hf] = *(const bf16x8*)(qp + ((long)h * NR + n0 + i * 16 + m16) * MF + hf * 32 + q * 8);

    for (int jt = 0; jt < ntile; jt++) {
      const int dt = (jt < 4) ? (w + jt * 4) : 16;
      const int d = dt * 16 + m16;
      const bf16* ph = hi + ((long)h * LTP + d) * MF + q * 8;
      const bf16* pl = lo + ((long)h * LTP + d) * MF + q * 8;
      const bf16x8 bh0 = *(const bf16x8*)ph, bh1 = *(const bf16x8*)(ph + 32);
      const bf16x8 bl0 = *(const bf16x8*)pl, bl1 = *(const bf16x8*)(pl + 32);
#pragma unroll
      for (int i = 0; i < 2; i++) {
        f32x4 a = {0.f, 0.f, 0.f, 0.f};
        a = __builtin_amdgcn_mfma_f32_16x16x32_bf16(af[i][1], bl1, a, 0, 0, 0);
        a = __builtin_amdgcn_mfma_f32_16x16x32_bf16(af[i][0], bl0, a, 0, 0, 0);
        a = __builtin_amdgcn_mfma_f32_16x16x32_bf16(af[i][1], bh1, a, 0, 0, 0);
        a = __builtin_amdgcn_mfma_f32_16x16x32_bf16(af[i][0], bh0, a, 0, 0, 0);
#pragma unroll
        for (int r = 0; r < 4; r++)
          zs[(i * 16 + q * 4 + r) * ZST + d] = a[r];
      }
    }
    __syncthreads();

    f32x4 zreg[8];
    float sz2 = 0.f, svz = 0.f, z0p = 0.f, v02p = 0.f;
#pragma unroll
    for (int it = 0; it < 8; it++) {
      zreg[it] = *(const f32x4*)&zs[erow * ZST + it * 32 + ecol];
#pragma unroll
      for (int c = 0; c < 4; c++) {
        sz2 = fmaf(zreg[it][c], zreg[it][c], sz2);
        svz = fmaf(vreg[it][c], zreg[it][c], svz);
      }
    }
    float z256 = 0.f;
    if (lead) {
      z256 = zs[erow * ZST + 256];
      sz2 = fmaf(z256, z256, sz2);
      svz = fmaf(v256, z256, svz);
      z0p = zreg[0][0];
      v02p = vreg[0][0] * vreg[0][0];
    }
#pragma unroll
    for (int off = 1; off < 8; off <<= 1) {
      sz2 += __shfl_xor(sz2, off);
      svz += __shfl_xor(svz, off);
      z0p += __shfl_xor(z0p, off);
      v02p += __shfl_xor(v02p, off);
    }
    const float a2 = 2.f * v02p - 1.f;
    const float mn = sz2 - 2.f * z0p * z0p;
    const float cf = 1.f / sqrtf(fabsf(mn + 1e-7f));
    const float ab = cf * svz;
    const float b2 = cf * cf * sz2;
    const float den = 1.f + 2.f * ab + a2 * b2;
    const float inv = 0.25f / (den + 1e-7f);
    const float sx = (1.f + 2.f * ab + b2) * inv;
    const float sy = (1.f - a2) * cf * inv;
#pragma unroll
    for (int it = 0; it < 8; it++)
#pragma unroll
      for (int c = 0; c < 4; c++)
        macc[it][c] = fmaf(sx, vreg[it][c], fmaf(sy, zreg[it][c], macc[it][c]));
    if (lead) macc256 = fmaf(sx, v256, fmaf(sy, z256, macc256));
    __syncthreads();
  }

  float sm2 = 0.f, m02p = 0.f;
#pragma unroll
  for (int it = 0; it < 8; it++)
#pragma unroll
    for (int c = 0; c < 4; c++) sm2 = fmaf(macc[it][c], macc[it][c], sm2);
  if (lead) {
    sm2 = fmaf(macc256, macc256, sm2);
    m02p = macc[0][0] * macc[0][0];
  }
#pragma unroll
  for (int off = 1; off < 8; off <<= 1) {
    sm2 += __shfl_xor(sm2, off);
    m02p += __shfl_xor(m02p, off);
  }
  const float fv = 1.f / sqrtf(fabsf(sm2 - 2.f * m02p) + 1e-7f);
  float* orow = o + (long)(n0 + erow) * DIN;
#pragma unroll
  for (int it = 0; it < 8; it++)
#pragma unroll
    for (int c = 0; c < 4; c++) orow[it * 32 + ecol + c] = macc[it][c] * fv;
  if (lead) orow[256] = macc256 * fv;
}

extern "C" void kernel_launch(void* const* d_in, const int* in_sizes, int n_in,
                              void* d_out, int out_size, void* d_ws, size_t ws_size,
                              hipStream_t stream) {
  const float* u    = (const float*)d_in[0];
  const float* ii   = (const float*)d_in[1];
  const float* Wk   = (const float*)d_in[2];
  const float* bk   = (const float*)d_in[3];
  const float* Wq   = (const float*)d_in[4];
  const float* bq   = (const float*)d_in[5];
  const float* Wv   = (const float*)d_in[6];
  const float* bv   = (const float*)d_in[7];
  const float* proj = (const float*)d_in[8];
  float* out = (float*)d_out;

  const long NV = (long)HH * NR * DIN;
  const long NF = (long)HH * NR * MF;
  const long NLT = (long)HH * LTP * MF;
  float* v_u = (float*)d_ws;
  float* v_i = v_u + NV;
  bf16* qp_u = (bf16*)(v_i + NV);
  bf16* kp_u = qp_u + NF;
  bf16* qp_i = kp_u + NF;
  bf16* kp_i = qp_i + NF;
  bf16* ltHi_u = kp_i + NF;
  bf16* ltLo_u = ltHi_u + NLT;
  bf16* ltHi_i = ltLo_u + NLT;
  bf16* ltLo_i = ltHi_i + NLT;
  bf16* xb_u  = ltLo_i + NLT;
  bf16* xb_i  = xb_u + (long)NR * KP;
  bf16* WbTq  = xb_i + (long)NR * KP;
  bf16* WbTk  = WbTq + 4 * 256 * KP;
  bf16* WbTv  = WbTk + 4 * 256 * KP;
  bf16* WpT   = WbTv + 4 * 256 * KP;   // 8 * 64 * KP bf16
  float* fr   = (float*)(WpT + 8 * 64 * KP);  // 16 * NR fp32
  float* part = (float*)xb_u;  // 16.4 MB split-K partials, alias xb (dead after feat)

  cvt_x_kernel<<<NR, KP, 0, stream>>>(u, xb_u);
  cvt_x_kernel<<<NR, KP, 0, stream>>>(ii, xb_i);
  cvt_w_kernel<<<dim3(1024, 3), KP, 0, stream>>>(Wq, Wk, Wv, WbTq, WbTk, WbTv);
  cvt_wp_kernel<<<dim3(KP, HH, 2), 64, 0, stream>>>(Wq, Wk, bq, bk, proj, WpT);

  proj4_kernel<<<dim3((NR + 63) / 64, HH, 6), 256, 0, stream>>>(
      xb_u, xb_i, WbTq, WbTk, WbTv, bq, bk, bv, v_u, v_i, fr);
  feat_kernel<<<dim3((NR + 127) / 128, HH, 4), 256, 0, stream>>>(
      xb_u, xb_i, WpT, fr, qp_u, kp_u, qp_i, kp_i);

  // side 0 (-> lastT_u) uses (v_i, kp_i); side 1 (-> lastT_i) uses (v_u, kp_u)
  last3_kernel<<<dim3(5, LKC, 8), 256, 0, stream>>>(v_i, kp_i, v_u, kp_u, part);
  reduce_last4<<<dim3(LTP, 8), 64, 0, stream>>>(part, ltHi_u, ltLo_u, ltHi_i, ltLo_i);

  fuse3_kernel<<<dim3(NR / 32, 2), 256, 0, stream>>>(
      qp_u, v_u, ltHi_u, ltLo_u, qp_i, v_i, ltHi_i, ltLo_i, out);
}